// Round 1
// baseline (1184.277 us; speedup 1.0000x reference)
//
#include <hip/hip_runtime.h>
#include <hip/hip_bf16.h>
#include <cstdint>
#include <cstddef>

// ---------------------------------------------------------------------------
// GCN: out = relu(agg(relu(agg(x)@W1+b1))@W2+b2) @ Wl + bl
// agg(v)[d] = sum_{e:dst=d} dinv[src]*dinv[d]*v[src] + dinv[d]^2*v[d]
// dinv[n] = rsqrt(1 + indegree(n))
// ---------------------------------------------------------------------------

__global__ void init_deg_kernel(float* __restrict__ deg, int n) {
    int i = blockIdx.x * blockDim.x + threadIdx.x;
    if (i < n) deg[i] = 1.0f;  // self-loop
}

__global__ void count_deg_kernel(const int* __restrict__ dst, float* __restrict__ deg, int e) {
    int i = blockIdx.x * blockDim.x + threadIdx.x;
    if (i < e) atomicAdd(&deg[dst[i]], 1.0f);  // integer-valued fp32 sums: exact & order-independent
}

// Single-block scan: dinv, exclusive prefix of in-degree (row_start), zero cursors.
__global__ __launch_bounds__(1024)
void scan_kernel(const float* __restrict__ deg, float* __restrict__ dinv,
                 int* __restrict__ row_start, int* __restrict__ cursor, int n) {
    __shared__ int sm[1024];
    __shared__ int carry_s;
    const int t = threadIdx.x;
    if (t == 0) carry_s = 0;
    __syncthreads();
    for (int base = 0; base < n; base += 1024) {
        int i = base + t;
        int v = 0;
        if (i < n) {
            float d = deg[i];
            dinv[i] = rsqrtf(d);
            cursor[i] = 0;
            v = (int)d - 1;  // edge count excluding the self-loop
        }
        sm[t] = v;
        __syncthreads();
        int carry = carry_s;
        for (int off = 1; off < 1024; off <<= 1) {
            int tv = (t >= off) ? sm[t - off] : 0;
            __syncthreads();
            sm[t] += tv;
            __syncthreads();
        }
        if (i < n) row_start[i] = carry + sm[t] - v;  // exclusive scan
        if (t == 1023) carry_s = carry + sm[1023];
        __syncthreads();
    }
    if (t == 0) row_start[n] = carry_s;
}

__global__ void bucket_kernel(const int* __restrict__ src, const int* __restrict__ dst,
                              const int* __restrict__ row_start, int* __restrict__ cursor,
                              int* __restrict__ csr, int e) {
    int i = blockIdx.x * blockDim.x + threadIdx.x;
    if (i < e) {
        int d = dst[i];
        int pos = atomicAdd(&cursor[d], 1);
        csr[row_start[d] + pos] = src[i];
    }
}

// One block (256 threads) per dst node; each thread owns F/256 feature lanes.
template <int F>
__global__ __launch_bounds__(256)
void agg_kernel(const float* __restrict__ xin, float* __restrict__ xout,
                const int* __restrict__ csr, const int* __restrict__ row_start,
                const float* __restrict__ dinv) {
    const int node = blockIdx.x;
    const int t = threadIdx.x;
    const float dn = dinv[node];
    const int beg = row_start[node];
    const int end = row_start[node + 1];
    constexpr int PF = F / 256;
    float acc[PF];
#pragma unroll
    for (int j = 0; j < PF; j++) acc[j] = 0.f;
    for (int i = beg; i < end; i++) {
        int s = csr[i];
        float w = dinv[s] * dn;
        const float* xs = xin + (size_t)s * F;
#pragma unroll
        for (int j = 0; j < PF; j++) acc[j] = fmaf(xs[t + j * 256], w, acc[j]);
    }
    const float* xn = xin + (size_t)node * F;
    const float ws = dn * dn;
#pragma unroll
    for (int j = 0; j < PF; j++) {
        xout[(size_t)node * F + t + j * 256] = fmaf(xn[t + j * 256], ws, acc[j]);
    }
}

// fp32 GEMM: C[M,N] = A[M,K] @ B[K,N] + bias, optional ReLU.
// 64x64 tile, BK=16, 256 threads, 4x4 micro-tile. A staged transposed in LDS.
template <bool RELU>
__global__ __launch_bounds__(256)
void gemm_bias_kernel(const float* __restrict__ A, const float* __restrict__ B,
                      const float* __restrict__ bias, float* __restrict__ C,
                      int M, int K, int N) {
    __shared__ float As[16][64];  // [k][m]
    __shared__ float Bs[16][64];  // [k][n]
    const int tid = threadIdx.x;
    const int m0 = blockIdx.y * 64;
    const int n0 = blockIdx.x * 64;
    const int tx = tid & 15, ty = tid >> 4;
    const int arow = tid >> 2, aq = (tid & 3) * 4;   // A: row 0..63, k-offset {0,4,8,12}
    const int brow = tid >> 4, bq = (tid & 15) * 4;  // B: k 0..15,  n-offset 0..60

    float c[4][4];
#pragma unroll
    for (int i = 0; i < 4; i++)
#pragma unroll
        for (int j = 0; j < 4; j++) c[i][j] = 0.f;

    for (int k0 = 0; k0 < K; k0 += 16) {
        float4 av = make_float4(0.f, 0.f, 0.f, 0.f);
        if (m0 + arow < M) av = *(const float4*)&A[(size_t)(m0 + arow) * K + k0 + aq];
        float4 bv = *(const float4*)&B[(size_t)(k0 + brow) * N + n0 + bq];
        __syncthreads();  // previous iteration's reads done
        As[aq + 0][arow] = av.x;
        As[aq + 1][arow] = av.y;
        As[aq + 2][arow] = av.z;
        As[aq + 3][arow] = av.w;
        *(float4*)&Bs[brow][bq] = bv;
        __syncthreads();
#pragma unroll
        for (int k = 0; k < 16; ++k) {
            float4 av2 = *(const float4*)&As[k][ty * 4];
            float4 bv2 = *(const float4*)&Bs[k][tx * 4];
            float a[4] = {av2.x, av2.y, av2.z, av2.w};
            float b[4] = {bv2.x, bv2.y, bv2.z, bv2.w};
#pragma unroll
            for (int i = 0; i < 4; i++)
#pragma unroll
                for (int j = 0; j < 4; j++) c[i][j] = fmaf(a[i], b[j], c[i][j]);
        }
    }

    const float4 bv = *(const float4*)&bias[n0 + tx * 4];
    const float bb[4] = {bv.x, bv.y, bv.z, bv.w};
#pragma unroll
    for (int i = 0; i < 4; i++) {
        int row = m0 + ty * 4 + i;
        if (row < M) {
            float4 v;
            float* vp = (float*)&v;
#pragma unroll
            for (int j = 0; j < 4; j++) {
                float val = c[i][j] + bb[j];
                if (RELU) val = fmaxf(val, 0.f);
                vp[j] = val;
            }
            *(float4*)&C[(size_t)row * N + n0 + tx * 4] = v;
        }
    }
}

extern "C" void kernel_launch(void* const* d_in, const int* in_sizes, int n_in,
                              void* d_out, int out_size, void* d_ws, size_t ws_size,
                              hipStream_t stream) {
    const float* x  = (const float*)d_in[0];
    const int*   ei = (const int*)d_in[1];
    const float* W1 = (const float*)d_in[2];
    const float* b1 = (const float*)d_in[3];
    const float* W2 = (const float*)d_in[4];
    const float* b2 = (const float*)d_in[5];
    const float* Wl = (const float*)d_in[6];
    const float* bl = (const float*)d_in[7];
    float* out = (float*)d_out;

    const int N = in_sizes[0] / 256;  // 50000
    const int E = in_sizes[1] / 2;    // 800000
    const int* src = ei;
    const int* dst = ei + E;

    // ---- workspace carve (256B-aligned regions) ----
    size_t off = 0;
    auto alloc = [&](size_t bytes) -> void* {
        void* p = (char*)d_ws + off;
        off += (bytes + 255) & ~(size_t)255;
        return p;
    };
    float* deg       = (float*)alloc((size_t)N * 4);
    float* dinv      = (float*)alloc((size_t)N * 4);
    int*   row_start = (int*)alloc((size_t)(N + 1) * 4);
    int*   cursor    = (int*)alloc((size_t)N * 4);
    int*   csr       = (int*)alloc((size_t)E * 4);
    float* bufA      = (float*)alloc((size_t)N * 512 * 4);  // a1[N,256] then a2[N,512]
    float* bufB      = (float*)alloc((size_t)N * 512 * 4);  // h1[N,512] then h2[N,512]
    (void)ws_size;

    // ---- graph structure (rebuilt every call; ws is not preserved) ----
    init_deg_kernel<<<(N + 255) / 256, 256, 0, stream>>>(deg, N);
    count_deg_kernel<<<(E + 255) / 256, 256, 0, stream>>>(dst, deg, E);
    scan_kernel<<<1, 1024, 0, stream>>>(deg, dinv, row_start, cursor, N);
    bucket_kernel<<<(E + 255) / 256, 256, 0, stream>>>(src, dst, row_start, cursor, csr, E);

    // ---- layer 1: aggregate(x) @ W1 + b1, relu ----
    agg_kernel<256><<<N, 256, 0, stream>>>(x, bufA, csr, row_start, dinv);
    dim3 g1(512 / 64, (N + 63) / 64);
    gemm_bias_kernel<true><<<g1, 256, 0, stream>>>(bufA, W1, b1, bufB, N, 256, 512);

    // ---- layer 2: aggregate(h1) @ W2 + b2, relu ----
    agg_kernel<512><<<N, 256, 0, stream>>>(bufB, bufA, csr, row_start, dinv);
    dim3 g2(512 / 64, (N + 63) / 64);
    gemm_bias_kernel<true><<<g2, 256, 0, stream>>>(bufA, W2, b2, bufB, N, 512, 512);

    // ---- output projection ----
    dim3 g3(64 / 64, (N + 63) / 64);
    gemm_bias_kernel<false><<<g3, 256, 0, stream>>>(bufB, Wl, bl, out, N, 512, 64);
}

// Round 2
// 832.471 us; speedup vs baseline: 1.4226x; 1.4226x over previous
//
#include <hip/hip_runtime.h>
#include <cstdint>
#include <cstddef>

typedef unsigned short u16;
typedef __attribute__((ext_vector_type(8))) short bf16x8;
typedef __attribute__((ext_vector_type(4))) float f32x4;

// ---------------- bf16 split helpers (hi + lo ≈ fp32, err ~2^-18) ----------
__device__ __forceinline__ u16 f2bf(float f) {
    union { float f; unsigned u; } v; v.f = f;
    unsigned u = v.u;
    return (u16)((u + 0x7FFFu + ((u >> 16) & 1u)) >> 16);  // RNE
}
__device__ __forceinline__ float bf2f(u16 h) {
    union { unsigned u; float f; } v; v.u = ((unsigned)h) << 16;
    return v.f;
}
__device__ __forceinline__ float bf2f_lo(unsigned w) {  // low u16 of packed word
    union { unsigned u; float f; } v; v.u = w << 16;
    return v.f;
}
__device__ __forceinline__ float bf2f_hi(unsigned w) {  // high u16 of packed word
    union { unsigned u; float f; } v; v.u = w & 0xFFFF0000u;
    return v.f;
}

// ---------------- graph setup ----------------------------------------------
__global__ void init_deg_kernel(float* __restrict__ deg, int n) {
    int i = blockIdx.x * blockDim.x + threadIdx.x;
    if (i < n) deg[i] = 1.0f;  // self-loop
}

__global__ void count_deg_kernel(const int* __restrict__ dst, float* __restrict__ deg, int e) {
    int i = blockIdx.x * blockDim.x + threadIdx.x;
    if (i < e) atomicAdd(&deg[dst[i]], 1.0f);  // integer-valued fp32: exact, order-independent
}

__global__ __launch_bounds__(1024)
void scan_kernel(const float* __restrict__ deg, float* __restrict__ dinv,
                 int* __restrict__ row_start, int* __restrict__ cursor, int n) {
    __shared__ int sm[1024];
    __shared__ int carry_s;
    const int t = threadIdx.x;
    if (t == 0) carry_s = 0;
    __syncthreads();
    for (int base = 0; base < n; base += 1024) {
        int i = base + t;
        int v = 0;
        if (i < n) {
            float d = deg[i];
            dinv[i] = rsqrtf(d);
            cursor[i] = 0;
            v = (int)d - 1;
        }
        sm[t] = v;
        __syncthreads();
        int carry = carry_s;
        for (int off = 1; off < 1024; off <<= 1) {
            int tv = (t >= off) ? sm[t - off] : 0;
            __syncthreads();
            sm[t] += tv;
            __syncthreads();
        }
        if (i < n) row_start[i] = carry + sm[t] - v;
        if (t == 1023) carry_s = carry + sm[1023];
        __syncthreads();
    }
    if (t == 0) row_start[n] = carry_s;
}

__global__ void bucket_kernel(const int* __restrict__ src, const int* __restrict__ dst,
                              const int* __restrict__ row_start, int* __restrict__ cursor,
                              int* __restrict__ csr, int e) {
    int i = blockIdx.x * blockDim.x + threadIdx.x;
    if (i < e) {
        int d = dst[i];
        int pos = atomicAdd(&cursor[d], 1);
        csr[row_start[d] + pos] = src[i];
    }
}

// ---------------- weight transpose + split: W[K,N] -> Bt{h,l}[N,K] ---------
__global__ void wsplit_kernel(const float* __restrict__ W, u16* __restrict__ bh,
                              u16* __restrict__ bl, int K, int N) {
    const int k8 = K >> 3;
    const int idx = blockIdx.x * blockDim.x + threadIdx.x;
    if (idx >= N * k8) return;
    const int n = idx / k8;
    const int k0 = (idx - n * k8) * 8;
    alignas(16) u16 h8[8];
    alignas(16) u16 l8[8];
#pragma unroll
    for (int j = 0; j < 8; j++) {
        const float v = W[(size_t)(k0 + j) * N + n];
        h8[j] = f2bf(v);
        l8[j] = f2bf(v - bf2f(h8[j]));
    }
    *(uint4*)(bh + (size_t)n * K + k0) = *(const uint4*)h8;
    *(uint4*)(bl + (size_t)n * K + k0) = *(const uint4*)l8;
}

// ---------------- aggregation: fp32 input (layer 1, F=256) -----------------
__global__ __launch_bounds__(256)
void agg_f32_kernel(const float* __restrict__ xin, u16* __restrict__ oh, u16* __restrict__ ol,
                    const int* __restrict__ csr, const int* __restrict__ rs,
                    const float* __restrict__ dinv) {
    const int node = blockIdx.x, t = threadIdx.x;
    const float dn = dinv[node];
    const int beg = rs[node], end = rs[node + 1];
    float a = 0.f;
    for (int i = beg; i < end; i++) {
        const int s = csr[i];
        a = fmaf(xin[(size_t)s * 256 + t], dinv[s] * dn, a);
    }
    a = fmaf(xin[(size_t)node * 256 + t], dn * dn, a);
    u16 h = f2bf(a), l = f2bf(a - bf2f(h));
    oh[(size_t)node * 256 + t] = h;
    ol[(size_t)node * 256 + t] = l;
}

// ---------------- aggregation: hi/lo input (layer 2, F=512) ----------------
__global__ __launch_bounds__(256)
void agg_bf_kernel(const u16* __restrict__ hin, const u16* __restrict__ lin,
                   u16* __restrict__ oh, u16* __restrict__ ol,
                   const int* __restrict__ csr, const int* __restrict__ rs,
                   const float* __restrict__ dinv) {
    const int node = blockIdx.x, t = threadIdx.x;
    const float dn = dinv[node];
    const int beg = rs[node], end = rs[node + 1];
    const int c0 = t * 2;
    float a0 = 0.f, a1 = 0.f;
    for (int i = beg; i < end; i++) {
        const int s = csr[i];
        const float w = dinv[s] * dn;
        const unsigned hw = *(const unsigned*)(hin + (size_t)s * 512 + c0);
        const unsigned lw = *(const unsigned*)(lin + (size_t)s * 512 + c0);
        a0 = fmaf(bf2f_lo(hw) + bf2f_lo(lw), w, a0);
        a1 = fmaf(bf2f_hi(hw) + bf2f_hi(lw), w, a1);
    }
    {
        const unsigned hw = *(const unsigned*)(hin + (size_t)node * 512 + c0);
        const unsigned lw = *(const unsigned*)(lin + (size_t)node * 512 + c0);
        const float ws = dn * dn;
        a0 = fmaf(bf2f_lo(hw) + bf2f_lo(lw), ws, a0);
        a1 = fmaf(bf2f_hi(hw) + bf2f_hi(lw), ws, a1);
    }
    u16 h0 = f2bf(a0), l0 = f2bf(a0 - bf2f(h0));
    u16 h1 = f2bf(a1), l1 = f2bf(a1 - bf2f(h1));
    *(unsigned*)(oh + (size_t)node * 512 + c0) = (unsigned)h0 | ((unsigned)h1 << 16);
    *(unsigned*)(ol + (size_t)node * 512 + c0) = (unsigned)l0 | ((unsigned)l1 << 16);
}

// ---------------- split-fp32 MFMA GEMM -------------------------------------
// C[M,Nn] = A[M,K] @ Bt[Nn,K]^T where A ≈ Ah+Al, Bt ≈ Bth+Btl (bf16 pairs).
// 3-term product: AhBh + AhBl + AlBh (drops 2^-18 AlBl).
// BM=128, BN=NFRAG*32, BK=32. 4 waves (2x2), 4 x NFRAG fragments per wave.
// LDS XOR slot-swizzle: slot' = slot ^ ((row>>1)&3) -> conflict-free writes,
// 2-way (free) fragment reads.
template <int NFRAG, bool RELU, bool SPLIT_OUT>
__global__ __launch_bounds__(256, 2)
void gemm_mfma_kernel(const u16* __restrict__ Ah, const u16* __restrict__ Al,
                      const u16* __restrict__ Bth, const u16* __restrict__ Btl,
                      const float* __restrict__ bias,
                      float* __restrict__ Cf, u16* __restrict__ Ch, u16* __restrict__ Cl,
                      int M, int K, int Nn) {
    constexpr int BM = 128;
    constexpr int BN = NFRAG * 32;
    __shared__ u16 sAh[BM * 32], sAl[BM * 32], sBh[BN * 32], sBl[BN * 32];

    // bijective XCD swizzle (m204): contiguous wg chunks per XCD
    const int gx = gridDim.x;
    const int nwg = gx * gridDim.y;
    const int orig = blockIdx.y * gx + blockIdx.x;
    const int q8 = nwg >> 3, r8 = nwg & 7;
    const int xcd = orig & 7, lin = orig >> 3;
    const int wg = (xcd < r8 ? xcd * (q8 + 1) : r8 * (q8 + 1) + (xcd - r8) * q8) + lin;
    const int mt = wg / gx;
    const int nt = wg - mt * gx;
    const int m0 = mt * BM, n0 = nt * BN;

    const int tid = threadIdx.x;
    const int lane = tid & 63;
    const int wid = tid >> 6;
    const int wm = (wid >> 1) * 64;
    const int wn = (wid & 1) * (NFRAG * 16);

    // staging descriptors: chunk = 16B; rows of 32 elems = 4 slots
    const int row_b = tid >> 2;  // 0..63
    const int slot = tid & 3;
    const int sw0 = slot ^ ((row_b >> 1) & 3);
    const int lA0 = row_b * 32 + sw0 * 8;  // ushort offset in LDS tile
    const int lA1 = lA0 + 64 * 32;         // rows +64: same swizzle bits
    const size_t gA0 = (size_t)(m0 + row_b) * K + slot * 8;
    const size_t gA1 = gA0 + (size_t)64 * K;
    const size_t gB0 = (size_t)(n0 + row_b) * K + slot * 8;
    const size_t gB1 = gB0 + (size_t)64 * K;  // only used when NFRAG==4

    // fragment LDS read offsets (constant per thread)
    int offA[4], offB[NFRAG];
    const int q = lane >> 4;
#pragma unroll
    for (int i = 0; i < 4; i++) {
        int r = wm + i * 16 + (lane & 15);
        offA[i] = r * 32 + ((q ^ ((r >> 1) & 3)) * 8);
    }
#pragma unroll
    for (int j = 0; j < NFRAG; j++) {
        int r = wn + j * 16 + (lane & 15);
        offB[j] = r * 32 + ((q ^ ((r >> 1) & 3)) * 8);
    }

    f32x4 acc[4][NFRAG];
#pragma unroll
    for (int i = 0; i < 4; i++)
#pragma unroll
        for (int j = 0; j < NFRAG; j++) acc[i][j] = (f32x4){0.f, 0.f, 0.f, 0.f};

    // preload k0 = 0 staging registers
    uint4 rA0h = *(const uint4*)(Ah + gA0);
    uint4 rA1h = *(const uint4*)(Ah + gA1);
    uint4 rA0l = *(const uint4*)(Al + gA0);
    uint4 rA1l = *(const uint4*)(Al + gA1);
    uint4 rB0h = *(const uint4*)(Bth + gB0);
    uint4 rB0l = *(const uint4*)(Btl + gB0);
    uint4 rB1h = {0, 0, 0, 0}, rB1l = {0, 0, 0, 0};
    if constexpr (NFRAG == 4) {
        rB1h = *(const uint4*)(Bth + gB1);
        rB1l = *(const uint4*)(Btl + gB1);
    }

    for (int k0 = 0; k0 < K; k0 += 32) {
        __syncthreads();  // previous compute phase done reading tiles
        *(uint4*)(sAh + lA0) = rA0h;
        *(uint4*)(sAh + lA1) = rA1h;
        *(uint4*)(sAl + lA0) = rA0l;
        *(uint4*)(sAl + lA1) = rA1l;
        *(uint4*)(sBh + lA0) = rB0h;
        *(uint4*)(sBl + lA0) = rB0l;
        if constexpr (NFRAG == 4) {
            *(uint4*)(sBh + lA1) = rB1h;
            *(uint4*)(sBl + lA1) = rB1l;
        }
        __syncthreads();  // tiles ready

        // issue next K-step's global loads early (overlap with MFMA below)
        if (k0 + 32 < K) {
            const int kn = k0 + 32;
            rA0h = *(const uint4*)(Ah + gA0 + kn);
            rA1h = *(const uint4*)(Ah + gA1 + kn);
            rA0l = *(const uint4*)(Al + gA0 + kn);
            rA1l = *(const uint4*)(Al + gA1 + kn);
            rB0h = *(const uint4*)(Bth + gB0 + kn);
            rB0l = *(const uint4*)(Btl + gB0 + kn);
            if constexpr (NFRAG == 4) {
                rB1h = *(const uint4*)(Bth + gB1 + kn);
                rB1l = *(const uint4*)(Btl + gB1 + kn);
            }
        }

        bf16x8 ah[4], al[4], bh[NFRAG], bl[NFRAG];
#pragma unroll
        for (int i = 0; i < 4; i++) {
            ah[i] = *(const bf16x8*)(sAh + offA[i]);
            al[i] = *(const bf16x8*)(sAl + offA[i]);
        }
#pragma unroll
        for (int j = 0; j < NFRAG; j++) {
            bh[j] = *(const bf16x8*)(sBh + offB[j]);
            bl[j] = *(const bf16x8*)(sBl + offB[j]);
        }
#pragma unroll
        for (int i = 0; i < 4; i++)
#pragma unroll
            for (int j = 0; j < NFRAG; j++) {
                acc[i][j] = __builtin_amdgcn_mfma_f32_16x16x32_bf16(ah[i], bh[j], acc[i][j], 0, 0, 0);
                acc[i][j] = __builtin_amdgcn_mfma_f32_16x16x32_bf16(ah[i], bl[j], acc[i][j], 0, 0, 0);
                acc[i][j] = __builtin_amdgcn_mfma_f32_16x16x32_bf16(al[i], bh[j], acc[i][j], 0, 0, 0);
            }
    }

    // epilogue: C row = (lane>>4)*4 + r, col = lane&15 (m89-verified mapping)
    const int cn = lane & 15;
    const int cm = (lane >> 4) * 4;
#pragma unroll
    for (int i = 0; i < 4; i++) {
#pragma unroll
        for (int j = 0; j < NFRAG; j++) {
            const int col = n0 + wn + j * 16 + cn;
            const float bv = bias[col];
#pragma unroll
            for (int r = 0; r < 4; r++) {
                const int row = m0 + wm + i * 16 + cm + r;
                if (row < M) {
                    float v = acc[i][j][r] + bv;
                    if (RELU) v = fmaxf(v, 0.f);
                    if (SPLIT_OUT) {
                        u16 h = f2bf(v);
                        u16 l = f2bf(v - bf2f(h));
                        Ch[(size_t)row * Nn + col] = h;
                        Cl[(size_t)row * Nn + col] = l;
                    } else {
                        Cf[(size_t)row * Nn + col] = v;
                    }
                }
            }
        }
    }
}

// ---------------------------------------------------------------------------
extern "C" void kernel_launch(void* const* d_in, const int* in_sizes, int n_in,
                              void* d_out, int out_size, void* d_ws, size_t ws_size,
                              hipStream_t stream) {
    const float* x  = (const float*)d_in[0];
    const int*   ei = (const int*)d_in[1];
    const float* W1 = (const float*)d_in[2];
    const float* b1 = (const float*)d_in[3];
    const float* W2 = (const float*)d_in[4];
    const float* b2 = (const float*)d_in[5];
    const float* Wl = (const float*)d_in[6];
    const float* bl = (const float*)d_in[7];
    float* out = (float*)d_out;

    const int N = in_sizes[0] / 256;  // 50000
    const int E = in_sizes[1] / 2;    // 800000
    const int Mpad = ((N + 127) / 128) * 128;  // 50048
    const int* src = ei;
    const int* dst = ei + E;

    size_t off = 0;
    auto alloc = [&](size_t bytes) -> void* {
        void* p = (char*)d_ws + off;
        off += (bytes + 255) & ~(size_t)255;
        return p;
    };
    float* deg       = (float*)alloc((size_t)N * 4);
    float* dinv      = (float*)alloc((size_t)N * 4);
    int*   row_start = (int*)alloc((size_t)(N + 1) * 4);
    int*   cursor    = (int*)alloc((size_t)N * 4);
    int*   csr       = (int*)alloc((size_t)E * 4);
    u16*   bt1h = (u16*)alloc((size_t)512 * 256 * 2);
    u16*   bt1l = (u16*)alloc((size_t)512 * 256 * 2);
    u16*   bt2h = (u16*)alloc((size_t)512 * 512 * 2);
    u16*   bt2l = (u16*)alloc((size_t)512 * 512 * 2);
    u16*   bt3h = (u16*)alloc((size_t)64 * 512 * 2);
    u16*   bt3l = (u16*)alloc((size_t)64 * 512 * 2);
    u16*   slabA = (u16*)alloc((size_t)Mpad * 512 * 2 * 2);  // 102.5 MB
    u16*   slabH = (u16*)alloc((size_t)Mpad * 512 * 2 * 2);  // 102.5 MB
    (void)ws_size;

    // views with lifetime-based aliasing
    u16* a1h = slabA;                              // [Mpad,256] live agg1->gemm1
    u16* a1l = slabA + (size_t)Mpad * 256;
    u16* a2h = slabA;                              // [Mpad,512] live agg2->gemm2
    u16* a2l = slabA + (size_t)Mpad * 512;
    u16* h1h = slabH;                              // [Mpad,512] live gemm1->agg2
    u16* h1l = slabH + (size_t)Mpad * 512;
    u16* h2h = slabH;                              // [Mpad,512] live gemm2->gemm3
    u16* h2l = slabH + (size_t)Mpad * 512;

    // graph structure (rebuilt every call)
    init_deg_kernel<<<(N + 255) / 256, 256, 0, stream>>>(deg, N);
    count_deg_kernel<<<(E + 255) / 256, 256, 0, stream>>>(dst, deg, E);
    scan_kernel<<<1, 1024, 0, stream>>>(deg, dinv, row_start, cursor, N);
    bucket_kernel<<<(E + 255) / 256, 256, 0, stream>>>(src, dst, row_start, cursor, csr, E);

    // weight split+transpose
    wsplit_kernel<<<(512 * 32 + 255) / 256, 256, 0, stream>>>(W1, bt1h, bt1l, 256, 512);
    wsplit_kernel<<<(512 * 64 + 255) / 256, 256, 0, stream>>>(W2, bt2h, bt2l, 512, 512);
    wsplit_kernel<<<(64 * 64 + 255) / 256, 256, 0, stream>>>(Wl, bt3h, bt3l, 512, 64);

    // layer 1
    agg_f32_kernel<<<N, 256, 0, stream>>>(x, a1h, a1l, csr, row_start, dinv);
    gemm_mfma_kernel<4, true, true><<<dim3(4, Mpad / 128), 256, 0, stream>>>(
        a1h, a1l, bt1h, bt1l, b1, nullptr, h1h, h1l, N, 256, 512);

    // layer 2
    agg_bf_kernel<<<N, 256, 0, stream>>>(h1h, h1l, a2h, a2l, csr, row_start, dinv);
    gemm_mfma_kernel<4, true, true><<<dim3(4, Mpad / 128), 256, 0, stream>>>(
        a2h, a2l, bt2h, bt2l, b2, nullptr, h2h, h2l, N, 512, 512);

    // output projection
    gemm_mfma_kernel<2, false, false><<<dim3(1, Mpad / 128), 256, 0, stream>>>(
        h2h, h2l, bt3h, bt3l, bl, out, nullptr, nullptr, N, 512, 64);
}

// Round 3
// 782.050 us; speedup vs baseline: 1.5143x; 1.0645x over previous
//
#include <hip/hip_runtime.h>
#include <cstdint>
#include <cstddef>

typedef unsigned short u16;
typedef __attribute__((ext_vector_type(8))) short bf16x8;
typedef __attribute__((ext_vector_type(4))) float f32x4;

// ---------------- bf16 split helpers (hi + lo ≈ fp32, err ~2^-18) ----------
__device__ __forceinline__ u16 f2bf(float f) {
    union { float f; unsigned u; } v; v.f = f;
    unsigned u = v.u;
    return (u16)((u + 0x7FFFu + ((u >> 16) & 1u)) >> 16);  // RNE
}
__device__ __forceinline__ float bf2f(u16 h) {
    union { unsigned u; float f; } v; v.u = ((unsigned)h) << 16;
    return v.f;
}
__device__ __forceinline__ float bf2f_lo(unsigned w) {
    union { unsigned u; float f; } v; v.u = w << 16;
    return v.f;
}
__device__ __forceinline__ float bf2f_hi(unsigned w) {
    union { unsigned u; float f; } v; v.u = w & 0xFFFF0000u;
    return v.f;
}

// ---------------- graph setup ----------------------------------------------
__global__ void init_deg_kernel(float* __restrict__ deg, int n) {
    int i = blockIdx.x * blockDim.x + threadIdx.x;
    if (i < n) deg[i] = 1.0f;  // self-loop
}

__global__ void count_deg_kernel(const int* __restrict__ dst, float* __restrict__ deg, int e) {
    int i = blockIdx.x * blockDim.x + threadIdx.x;
    if (i < e) atomicAdd(&deg[dst[i]], 1.0f);  // integer-valued fp32: exact, order-independent
}

__global__ __launch_bounds__(1024)
void scan_kernel(const float* __restrict__ deg, float* __restrict__ dinv,
                 int* __restrict__ row_start, int* __restrict__ cursor, int n) {
    __shared__ int sm[1024];
    __shared__ int carry_s;
    const int t = threadIdx.x;
    if (t == 0) carry_s = 0;
    __syncthreads();
    for (int base = 0; base < n; base += 1024) {
        int i = base + t;
        int v = 0;
        if (i < n) {
            float d = deg[i];
            dinv[i] = rsqrtf(d);
            cursor[i] = 0;
            v = (int)d - 1;
        }
        sm[t] = v;
        __syncthreads();
        int carry = carry_s;
        for (int off = 1; off < 1024; off <<= 1) {
            int tv = (t >= off) ? sm[t - off] : 0;
            __syncthreads();
            sm[t] += tv;
            __syncthreads();
        }
        if (i < n) row_start[i] = carry + sm[t] - v;
        if (t == 1023) carry_s = carry + sm[1023];
        __syncthreads();
    }
    if (t == 0) row_start[n] = carry_s;
}

// bucket + precompute per-edge weight dinv[src]*dinv[dst]
__global__ void bucket_kernel(const int* __restrict__ src, const int* __restrict__ dst,
                              const int* __restrict__ row_start, int* __restrict__ cursor,
                              int* __restrict__ csr, float* __restrict__ csr_w,
                              const float* __restrict__ dinv, int e) {
    int i = blockIdx.x * blockDim.x + threadIdx.x;
    if (i < e) {
        int d = dst[i];
        int s = src[i];
        int pos = atomicAdd(&cursor[d], 1);
        int at = row_start[d] + pos;
        csr[at] = s;
        csr_w[at] = dinv[s] * dinv[d];
    }
}

// ---------------- weight transpose + split: W[K,N] -> Bt{h,l}[N,K] ---------
__global__ void wsplit_kernel(const float* __restrict__ W, u16* __restrict__ bh,
                              u16* __restrict__ bl, int K, int N) {
    const int k8 = K >> 3;
    const int idx = blockIdx.x * blockDim.x + threadIdx.x;
    if (idx >= N * k8) return;
    const int n = idx / k8;
    const int k0 = (idx - n * k8) * 8;
    alignas(16) u16 h8[8];
    alignas(16) u16 l8[8];
#pragma unroll
    for (int j = 0; j < 8; j++) {
        const float v = W[(size_t)(k0 + j) * N + n];
        h8[j] = f2bf(v);
        l8[j] = f2bf(v - bf2f(h8[j]));
    }
    *(uint4*)(bh + (size_t)n * K + k0) = *(const uint4*)h8;
    *(uint4*)(bl + (size_t)n * K + k0) = *(const uint4*)l8;
}

// ---------------- aggregation: fp32 input (layer 1, F=256) -----------------
// 128 threads/node, 2 feats/thread (float2), edge loop unrolled x8.
__global__ __launch_bounds__(128)
void agg_f32_kernel(const float* __restrict__ xin, u16* __restrict__ oh, u16* __restrict__ ol,
                    const int* __restrict__ csr, const float* __restrict__ csr_w,
                    const int* __restrict__ rs, const float* __restrict__ dinv) {
    const int node = blockIdx.x, t = threadIdx.x;
    const int beg = rs[node], end = rs[node + 1];
    const int c0 = t * 2;
    float a0 = 0.f, a1 = 0.f;
    int i = beg;
    for (; i + 8 <= end; i += 8) {
        int s[8];
        float w[8];
        float2 v[8];
#pragma unroll
        for (int u = 0; u < 8; u++) { s[u] = csr[i + u]; w[u] = csr_w[i + u]; }
#pragma unroll
        for (int u = 0; u < 8; u++) v[u] = *(const float2*)(xin + (size_t)s[u] * 256 + c0);
#pragma unroll
        for (int u = 0; u < 8; u++) {
            a0 = fmaf(v[u].x, w[u], a0);
            a1 = fmaf(v[u].y, w[u], a1);
        }
    }
    for (; i < end; i++) {
        const int sv = csr[i];
        const float w = csr_w[i];
        float2 v = *(const float2*)(xin + (size_t)sv * 256 + c0);
        a0 = fmaf(v.x, w, a0);
        a1 = fmaf(v.y, w, a1);
    }
    {
        const float dn = dinv[node];
        const float ws = dn * dn;
        float2 v = *(const float2*)(xin + (size_t)node * 256 + c0);
        a0 = fmaf(v.x, ws, a0);
        a1 = fmaf(v.y, ws, a1);
    }
    u16 h0 = f2bf(a0), l0 = f2bf(a0 - bf2f(h0));
    u16 h1 = f2bf(a1), l1 = f2bf(a1 - bf2f(h1));
    *(unsigned*)(oh + (size_t)node * 256 + c0) = (unsigned)h0 | ((unsigned)h1 << 16);
    *(unsigned*)(ol + (size_t)node * 256 + c0) = (unsigned)l0 | ((unsigned)l1 << 16);
}

// ---------------- aggregation: hi/lo input (layer 2, F=512) ----------------
// 128 threads/node, 4 feats/thread (uint2 hi + uint2 lo), edge loop unrolled x4.
__global__ __launch_bounds__(128)
void agg_bf_kernel(const u16* __restrict__ hin, const u16* __restrict__ lin,
                   u16* __restrict__ oh, u16* __restrict__ ol,
                   const int* __restrict__ csr, const float* __restrict__ csr_w,
                   const int* __restrict__ rs, const float* __restrict__ dinv) {
    const int node = blockIdx.x, t = threadIdx.x;
    const int beg = rs[node], end = rs[node + 1];
    const int c0 = t * 4;
    float a0 = 0.f, a1 = 0.f, a2 = 0.f, a3 = 0.f;
    int i = beg;
    for (; i + 4 <= end; i += 4) {
        int s[4];
        float w[4];
        uint2 hv[4], lv[4];
#pragma unroll
        for (int u = 0; u < 4; u++) { s[u] = csr[i + u]; w[u] = csr_w[i + u]; }
#pragma unroll
        for (int u = 0; u < 4; u++) {
            const size_t base = (size_t)s[u] * 512 + c0;
            hv[u] = *(const uint2*)(hin + base);
            lv[u] = *(const uint2*)(lin + base);
        }
#pragma unroll
        for (int u = 0; u < 4; u++) {
            a0 = fmaf(bf2f_lo(hv[u].x) + bf2f_lo(lv[u].x), w[u], a0);
            a1 = fmaf(bf2f_hi(hv[u].x) + bf2f_hi(lv[u].x), w[u], a1);
            a2 = fmaf(bf2f_lo(hv[u].y) + bf2f_lo(lv[u].y), w[u], a2);
            a3 = fmaf(bf2f_hi(hv[u].y) + bf2f_hi(lv[u].y), w[u], a3);
        }
    }
    for (; i < end; i++) {
        const int sv = csr[i];
        const float w = csr_w[i];
        const size_t base = (size_t)sv * 512 + c0;
        uint2 hv = *(const uint2*)(hin + base);
        uint2 lv = *(const uint2*)(lin + base);
        a0 = fmaf(bf2f_lo(hv.x) + bf2f_lo(lv.x), w, a0);
        a1 = fmaf(bf2f_hi(hv.x) + bf2f_hi(lv.x), w, a1);
        a2 = fmaf(bf2f_lo(hv.y) + bf2f_lo(lv.y), w, a2);
        a3 = fmaf(bf2f_hi(hv.y) + bf2f_hi(lv.y), w, a3);
    }
    {
        const float dn = dinv[node];
        const float ws = dn * dn;
        const size_t base = (size_t)node * 512 + c0;
        uint2 hv = *(const uint2*)(hin + base);
        uint2 lv = *(const uint2*)(lin + base);
        a0 = fmaf(bf2f_lo(hv.x) + bf2f_lo(lv.x), ws, a0);
        a1 = fmaf(bf2f_hi(hv.x) + bf2f_hi(lv.x), ws, a1);
        a2 = fmaf(bf2f_lo(hv.y) + bf2f_lo(lv.y), ws, a2);
        a3 = fmaf(bf2f_hi(hv.y) + bf2f_hi(lv.y), ws, a3);
    }
    u16 h0 = f2bf(a0), l0 = f2bf(a0 - bf2f(h0));
    u16 h1 = f2bf(a1), l1 = f2bf(a1 - bf2f(h1));
    u16 h2 = f2bf(a2), l2 = f2bf(a2 - bf2f(h2));
    u16 h3 = f2bf(a3), l3 = f2bf(a3 - bf2f(h3));
    uint2 ho, lo;
    ho.x = (unsigned)h0 | ((unsigned)h1 << 16);
    ho.y = (unsigned)h2 | ((unsigned)h3 << 16);
    lo.x = (unsigned)l0 | ((unsigned)l1 << 16);
    lo.y = (unsigned)l2 | ((unsigned)l3 << 16);
    *(uint2*)(oh + (size_t)node * 512 + c0) = ho;
    *(uint2*)(ol + (size_t)node * 512 + c0) = lo;
}

// ---------------- split-fp32 MFMA GEMM -------------------------------------
// C[M,Nn] = A[M,K] @ Bt[Nn,K]^T with A ≈ Ah+Al, Bt ≈ Bth+Btl (bf16 pairs).
// 3-term product: AhBh + AhBl + AlBh. BM=128, BN=NFRAG*32, BK=32. 4 waves 2x2.
template <int NFRAG, bool RELU, bool SPLIT_OUT>
__global__ __launch_bounds__(256, 2)
void gemm_mfma_kernel(const u16* __restrict__ Ah, const u16* __restrict__ Al,
                      const u16* __restrict__ Bth, const u16* __restrict__ Btl,
                      const float* __restrict__ bias,
                      float* __restrict__ Cf, u16* __restrict__ Ch, u16* __restrict__ Cl,
                      int M, int K, int Nn) {
    constexpr int BM = 128;
    constexpr int BN = NFRAG * 32;
    __shared__ u16 sAh[BM * 32], sAl[BM * 32], sBh[BN * 32], sBl[BN * 32];

    const int gx = gridDim.x;
    const int nwg = gx * gridDim.y;
    const int orig = blockIdx.y * gx + blockIdx.x;
    const int q8 = nwg >> 3, r8 = nwg & 7;
    const int xcd = orig & 7, lin = orig >> 3;
    const int wg = (xcd < r8 ? xcd * (q8 + 1) : r8 * (q8 + 1) + (xcd - r8) * q8) + lin;
    const int mt = wg / gx;
    const int nt = wg - mt * gx;
    const int m0 = mt * BM, n0 = nt * BN;

    const int tid = threadIdx.x;
    const int lane = tid & 63;
    const int wid = tid >> 6;
    const int wm = (wid >> 1) * 64;
    const int wn = (wid & 1) * (NFRAG * 16);

    const int row_b = tid >> 2;
    const int slot = tid & 3;
    const int sw0 = slot ^ ((row_b >> 1) & 3);
    const int lA0 = row_b * 32 + sw0 * 8;
    const int lA1 = lA0 + 64 * 32;
    const size_t gA0 = (size_t)(m0 + row_b) * K + slot * 8;
    const size_t gA1 = gA0 + (size_t)64 * K;
    const size_t gB0 = (size_t)(n0 + row_b) * K + slot * 8;
    const size_t gB1 = gB0 + (size_t)64 * K;

    int offA[4], offB[NFRAG];
    const int q = lane >> 4;
#pragma unroll
    for (int i = 0; i < 4; i++) {
        int r = wm + i * 16 + (lane & 15);
        offA[i] = r * 32 + ((q ^ ((r >> 1) & 3)) * 8);
    }
#pragma unroll
    for (int j = 0; j < NFRAG; j++) {
        int r = wn + j * 16 + (lane & 15);
        offB[j] = r * 32 + ((q ^ ((r >> 1) & 3)) * 8);
    }

    f32x4 acc[4][NFRAG];
#pragma unroll
    for (int i = 0; i < 4; i++)
#pragma unroll
        for (int j = 0; j < NFRAG; j++) acc[i][j] = (f32x4){0.f, 0.f, 0.f, 0.f};

    uint4 rA0h = *(const uint4*)(Ah + gA0);
    uint4 rA1h = *(const uint4*)(Ah + gA1);
    uint4 rA0l = *(const uint4*)(Al + gA0);
    uint4 rA1l = *(const uint4*)(Al + gA1);
    uint4 rB0h = *(const uint4*)(Bth + gB0);
    uint4 rB0l = *(const uint4*)(Btl + gB0);
    uint4 rB1h = {0, 0, 0, 0}, rB1l = {0, 0, 0, 0};
    if constexpr (NFRAG == 4) {
        rB1h = *(const uint4*)(Bth + gB1);
        rB1l = *(const uint4*)(Btl + gB1);
    }

    for (int k0 = 0; k0 < K; k0 += 32) {
        __syncthreads();
        *(uint4*)(sAh + lA0) = rA0h;
        *(uint4*)(sAh + lA1) = rA1h;
        *(uint4*)(sAl + lA0) = rA0l;
        *(uint4*)(sAl + lA1) = rA1l;
        *(uint4*)(sBh + lA0) = rB0h;
        *(uint4*)(sBl + lA0) = rB0l;
        if constexpr (NFRAG == 4) {
            *(uint4*)(sBh + lA1) = rB1h;
            *(uint4*)(sBl + lA1) = rB1l;
        }
        __syncthreads();

        if (k0 + 32 < K) {
            const int kn = k0 + 32;
            rA0h = *(const uint4*)(Ah + gA0 + kn);
            rA1h = *(const uint4*)(Ah + gA1 + kn);
            rA0l = *(const uint4*)(Al + gA0 + kn);
            rA1l = *(const uint4*)(Al + gA1 + kn);
            rB0h = *(const uint4*)(Bth + gB0 + kn);
            rB0l = *(const uint4*)(Btl + gB0 + kn);
            if constexpr (NFRAG == 4) {
                rB1h = *(const uint4*)(Bth + gB1 + kn);
                rB1l = *(const uint4*)(Btl + gB1 + kn);
            }
        }

        bf16x8 ah[4], al[4], bh[NFRAG], bl[NFRAG];
#pragma unroll
        for (int i = 0; i < 4; i++) {
            ah[i] = *(const bf16x8*)(sAh + offA[i]);
            al[i] = *(const bf16x8*)(sAl + offA[i]);
        }
#pragma unroll
        for (int j = 0; j < NFRAG; j++) {
            bh[j] = *(const bf16x8*)(sBh + offB[j]);
            bl[j] = *(const bf16x8*)(sBl + offB[j]);
        }
#pragma unroll
        for (int i = 0; i < 4; i++)
#pragma unroll
            for (int j = 0; j < NFRAG; j++) {
                acc[i][j] = __builtin_amdgcn_mfma_f32_16x16x32_bf16(ah[i], bh[j], acc[i][j], 0, 0, 0);
                acc[i][j] = __builtin_amdgcn_mfma_f32_16x16x32_bf16(ah[i], bl[j], acc[i][j], 0, 0, 0);
                acc[i][j] = __builtin_amdgcn_mfma_f32_16x16x32_bf16(al[i], bh[j], acc[i][j], 0, 0, 0);
            }
    }

    const int cn = lane & 15;
    const int cm = (lane >> 4) * 4;
#pragma unroll
    for (int i = 0; i < 4; i++) {
#pragma unroll
        for (int j = 0; j < NFRAG; j++) {
            const int col = n0 + wn + j * 16 + cn;
            const float bv = bias[col];
#pragma unroll
            for (int r = 0; r < 4; r++) {
                const int row = m0 + wm + i * 16 + cm + r;
                if (row < M) {
                    float v = acc[i][j][r] + bv;
                    if (RELU) v = fmaxf(v, 0.f);
                    if (SPLIT_OUT) {
                        u16 h = f2bf(v);
                        u16 l = f2bf(v - bf2f(h));
                        Ch[(size_t)row * Nn + col] = h;
                        Cl[(size_t)row * Nn + col] = l;
                    } else {
                        Cf[(size_t)row * Nn + col] = v;
                    }
                }
            }
        }
    }
}

// ---------------------------------------------------------------------------
extern "C" void kernel_launch(void* const* d_in, const int* in_sizes, int n_in,
                              void* d_out, int out_size, void* d_ws, size_t ws_size,
                              hipStream_t stream) {
    const float* x  = (const float*)d_in[0];
    const int*   ei = (const int*)d_in[1];
    const float* W1 = (const float*)d_in[2];
    const float* b1 = (const float*)d_in[3];
    const float* W2 = (const float*)d_in[4];
    const float* b2 = (const float*)d_in[5];
    const float* Wl = (const float*)d_in[6];
    const float* bl = (const float*)d_in[7];
    float* out = (float*)d_out;

    const int N = in_sizes[0] / 256;  // 50000
    const int E = in_sizes[1] / 2;    // 800000
    const int Mpad = ((N + 127) / 128) * 128;  // 50048
    const int* src = ei;
    const int* dst = ei + E;

    size_t off = 0;
    auto alloc = [&](size_t bytes) -> void* {
        void* p = (char*)d_ws + off;
        off += (bytes + 255) & ~(size_t)255;
        return p;
    };
    float* deg       = (float*)alloc((size_t)N * 4);
    float* dinv      = (float*)alloc((size_t)N * 4);
    int*   row_start = (int*)alloc((size_t)(N + 1) * 4);
    int*   cursor    = (int*)alloc((size_t)N * 4);
    int*   csr       = (int*)alloc((size_t)E * 4);
    float* csr_w     = (float*)alloc((size_t)E * 4);
    u16*   bt1h = (u16*)alloc((size_t)512 * 256 * 2);
    u16*   bt1l = (u16*)alloc((size_t)512 * 256 * 2);
    u16*   bt2h = (u16*)alloc((size_t)512 * 512 * 2);
    u16*   bt2l = (u16*)alloc((size_t)512 * 512 * 2);
    u16*   bt3h = (u16*)alloc((size_t)64 * 512 * 2);
    u16*   bt3l = (u16*)alloc((size_t)64 * 512 * 2);
    u16*   slabA = (u16*)alloc((size_t)Mpad * 512 * 2 * 2);
    u16*   slabH = (u16*)alloc((size_t)Mpad * 512 * 2 * 2);
    (void)ws_size;

    u16* a1h = slabA;
    u16* a1l = slabA + (size_t)Mpad * 256;
    u16* a2h = slabA;
    u16* a2l = slabA + (size_t)Mpad * 512;
    u16* h1h = slabH;
    u16* h1l = slabH + (size_t)Mpad * 512;
    u16* h2h = slabH;
    u16* h2l = slabH + (size_t)Mpad * 512;

    init_deg_kernel<<<(N + 255) / 256, 256, 0, stream>>>(deg, N);
    count_deg_kernel<<<(E + 255) / 256, 256, 0, stream>>>(dst, deg, E);
    scan_kernel<<<1, 1024, 0, stream>>>(deg, dinv, row_start, cursor, N);
    bucket_kernel<<<(E + 255) / 256, 256, 0, stream>>>(src, dst, row_start, cursor, csr, csr_w, dinv, E);

    wsplit_kernel<<<(512 * 32 + 255) / 256, 256, 0, stream>>>(W1, bt1h, bt1l, 256, 512);
    wsplit_kernel<<<(512 * 64 + 255) / 256, 256, 0, stream>>>(W2, bt2h, bt2l, 512, 512);
    wsplit_kernel<<<(64 * 64 + 255) / 256, 256, 0, stream>>>(Wl, bt3h, bt3l, 512, 64);

    agg_f32_kernel<<<N, 128, 0, stream>>>(x, a1h, a1l, csr, csr_w, row_start, dinv);
    gemm_mfma_kernel<4, true, true><<<dim3(4, Mpad / 128), 256, 0, stream>>>(
        a1h, a1l, bt1h, bt1l, b1, nullptr, h1h, h1l, N, 256, 512);

    agg_bf_kernel<<<N, 128, 0, stream>>>(h1h, h1l, a2h, a2l, csr, csr_w, row_start, dinv);
    gemm_mfma_kernel<4, true, true><<<dim3(4, Mpad / 128), 256, 0, stream>>>(
        a2h, a2l, bt2h, bt2l, b2, nullptr, h2h, h2l, N, 512, 512);

    gemm_mfma_kernel<2, false, false><<<dim3(1, Mpad / 128), 256, 0, stream>>>(
        h2h, h2l, bt3h, bt3l, bl, out, nullptr, nullptr, N, 512, 64);
}

// Round 5
// 638.987 us; speedup vs baseline: 1.8534x; 1.2239x over previous
//
#include <hip/hip_runtime.h>
#include <cstdint>
#include <cstddef>

typedef unsigned short u16;
typedef __attribute__((ext_vector_type(8))) short bf16x8;
typedef __attribute__((ext_vector_type(4))) float f32x4;
typedef __attribute__((ext_vector_type(2))) unsigned u32x2;
typedef __attribute__((ext_vector_type(4))) unsigned u32x4;

// ---------------- bf16 split helpers ---------------------------------------
__device__ __forceinline__ u16 f2bf(float f) {
    union { float f; unsigned u; } v; v.f = f;
    unsigned u = v.u;
    return (u16)((u + 0x7FFFu + ((u >> 16) & 1u)) >> 16);  // RNE
}
__device__ __forceinline__ float bf2f(u16 h) {
    union { unsigned u; float f; } v; v.u = ((unsigned)h) << 16;
    return v.f;
}
__device__ __forceinline__ float bf2f_lo(unsigned w) {
    union { unsigned u; float f; } v; v.u = w << 16;
    return v.f;
}
__device__ __forceinline__ float bf2f_hi(unsigned w) {
    union { unsigned u; float f; } v; v.u = w & 0xFFFF0000u;
    return v.f;
}

// ---------------- graph setup ----------------------------------------------
__global__ void init_deg_kernel(float* __restrict__ deg, int n) {
    int i = blockIdx.x * blockDim.x + threadIdx.x;
    if (i < n) deg[i] = 1.0f;  // self-loop
}

__global__ void count_deg_kernel(const int* __restrict__ dst, float* __restrict__ deg, int e) {
    int i = blockIdx.x * blockDim.x + threadIdx.x;
    if (i < e) atomicAdd(&deg[dst[i]], 1.0f);  // integer-valued fp32: exact, order-independent
}

__global__ __launch_bounds__(1024)
void scan_kernel(const float* __restrict__ deg, float* __restrict__ dinv,
                 int* __restrict__ row_start, int* __restrict__ cursor, int n) {
    __shared__ int sm[1024];
    __shared__ int carry_s;
    const int t = threadIdx.x;
    if (t == 0) carry_s = 0;
    __syncthreads();
    for (int base = 0; base < n; base += 1024) {
        int i = base + t;
        int v = 0;
        if (i < n) {
            float d = deg[i];
            dinv[i] = rsqrtf(d);
            cursor[i] = 0;
            v = (int)d - 1;
        }
        sm[t] = v;
        __syncthreads();
        int carry = carry_s;
        for (int off = 1; off < 1024; off <<= 1) {
            int tv = (t >= off) ? sm[t - off] : 0;
            __syncthreads();
            sm[t] += tv;
            __syncthreads();
        }
        if (i < n) row_start[i] = carry + sm[t] - v;
        if (t == 1023) carry_s = carry + sm[1023];
        __syncthreads();
    }
    if (t == 0) row_start[n] = carry_s;
}

__global__ void bucket_kernel(const int* __restrict__ src, const int* __restrict__ dst,
                              const int* __restrict__ row_start, int* __restrict__ cursor,
                              int* __restrict__ csr, float* __restrict__ csr_w,
                              const float* __restrict__ dinv, int e) {
    int i = blockIdx.x * blockDim.x + threadIdx.x;
    if (i < e) {
        int d = dst[i];
        int s = src[i];
        int pos = atomicAdd(&cursor[d], 1);
        int at = row_start[d] + pos;
        csr[at] = s;
        csr_w[at] = dinv[s] * dinv[d];
    }
}

// ---------------- weight transpose + split: W[K,N] -> Bt{h,l}[N,K] ---------
__global__ void wsplit_kernel(const float* __restrict__ W, u16* __restrict__ bh,
                              u16* __restrict__ bl, int K, int N) {
    const int k8 = K >> 3;
    const int idx = blockIdx.x * blockDim.x + threadIdx.x;
    if (idx >= N * k8) return;
    const int n = idx / k8;
    const int k0 = (idx - n * k8) * 8;
    alignas(16) u16 h8[8];
    alignas(16) u16 l8[8];
#pragma unroll
    for (int j = 0; j < 8; j++) {
        const float v = W[(size_t)(k0 + j) * N + n];
        h8[j] = f2bf(v);
        l8[j] = f2bf(v - bf2f(h8[j]));
    }
    *(uint4*)(bh + (size_t)n * K + k0) = *(const uint4*)h8;
    *(uint4*)(bl + (size_t)n * K + k0) = *(const uint4*)l8;
}

// ---------------- x -> bf16 copy (gather-side compression) -----------------
__global__ void xsplit_kernel(const float* __restrict__ x, u16* __restrict__ xh, size_t total8) {
    const size_t idx = (size_t)blockIdx.x * blockDim.x + threadIdx.x;
    if (idx >= total8) return;
    const float4 v0 = *(const float4*)(x + idx * 8);
    const float4 v1 = *(const float4*)(x + idx * 8 + 4);
    alignas(16) u16 h8[8];
    h8[0] = f2bf(v0.x); h8[1] = f2bf(v0.y); h8[2] = f2bf(v0.z); h8[3] = f2bf(v0.w);
    h8[4] = f2bf(v1.x); h8[5] = f2bf(v1.y); h8[6] = f2bf(v1.z); h8[7] = f2bf(v1.w);
    *(uint4*)(xh + idx * 8) = *(const uint4*)h8;
}

// ---------------- layer-1 aggregation (x bf16 gather, F=256) ---------------
// wave per node; lane owns 4 feats (uint2 bf16). Self term from exact fp32 x.
__global__ __launch_bounds__(256)
void agg_x_kernel(const float* __restrict__ x, const u16* __restrict__ xh,
                  u16* __restrict__ oh, u16* __restrict__ ol,
                  const int* __restrict__ csr, const float* __restrict__ csr_w,
                  const int* __restrict__ rs, const float* __restrict__ dinv, int n) {
    const int node = blockIdx.x * 4 + (threadIdx.x >> 6);
    if (node >= n) return;
    const int lane = threadIdx.x & 63;
    const int c0 = lane * 4;
    const int beg = rs[node], end = rs[node + 1];
    float a0 = 0.f, a1 = 0.f, a2 = 0.f, a3 = 0.f;
    int i = beg;
    for (; i + 4 <= end; i += 4) {
        int s[4];
        float w[4];
        uint2 hv[4];
#pragma unroll
        for (int u = 0; u < 4; u++) {
            s[u] = __builtin_nontemporal_load(csr + i + u);
            w[u] = __builtin_nontemporal_load(csr_w + i + u);
        }
#pragma unroll
        for (int u = 0; u < 4; u++) hv[u] = *(const uint2*)(xh + (size_t)s[u] * 256 + c0);
#pragma unroll
        for (int u = 0; u < 4; u++) {
            a0 = fmaf(bf2f_lo(hv[u].x), w[u], a0);
            a1 = fmaf(bf2f_hi(hv[u].x), w[u], a1);
            a2 = fmaf(bf2f_lo(hv[u].y), w[u], a2);
            a3 = fmaf(bf2f_hi(hv[u].y), w[u], a3);
        }
    }
    for (; i < end; i++) {
        const int sv = csr[i];
        const float w = csr_w[i];
        uint2 hv = *(const uint2*)(xh + (size_t)sv * 256 + c0);
        a0 = fmaf(bf2f_lo(hv.x), w, a0);
        a1 = fmaf(bf2f_hi(hv.x), w, a1);
        a2 = fmaf(bf2f_lo(hv.y), w, a2);
        a3 = fmaf(bf2f_hi(hv.y), w, a3);
    }
    {
        const float dn = dinv[node];
        const float ws = dn * dn;
        const float4 xv = *(const float4*)(x + (size_t)node * 256 + c0);
        a0 = fmaf(xv.x, ws, a0);
        a1 = fmaf(xv.y, ws, a1);
        a2 = fmaf(xv.z, ws, a2);
        a3 = fmaf(xv.w, ws, a3);
    }
    u16 h0 = f2bf(a0), l0 = f2bf(a0 - bf2f(h0));
    u16 h1 = f2bf(a1), l1 = f2bf(a1 - bf2f(h1));
    u16 h2 = f2bf(a2), l2 = f2bf(a2 - bf2f(h2));
    u16 h3 = f2bf(a3), l3 = f2bf(a3 - bf2f(h3));
    u32x2 ho, lo;
    ho.x = (unsigned)h0 | ((unsigned)h1 << 16);
    ho.y = (unsigned)h2 | ((unsigned)h3 << 16);
    lo.x = (unsigned)l0 | ((unsigned)l1 << 16);
    lo.y = (unsigned)l2 | ((unsigned)l3 << 16);
    __builtin_nontemporal_store(ho, (u32x2*)(oh + (size_t)node * 256 + c0));
    __builtin_nontemporal_store(lo, (u32x2*)(ol + (size_t)node * 256 + c0));
}

// ---------------- layer-2 aggregation (h1 bf16 gather, F=512) --------------
// wave per node; lane owns 8 feats (uint4 bf16).
__global__ __launch_bounds__(256)
void agg_h_kernel(const u16* __restrict__ hin,
                  u16* __restrict__ oh, u16* __restrict__ ol,
                  const int* __restrict__ csr, const float* __restrict__ csr_w,
                  const int* __restrict__ rs, const float* __restrict__ dinv, int n) {
    const int node = blockIdx.x * 4 + (threadIdx.x >> 6);
    if (node >= n) return;
    const int lane = threadIdx.x & 63;
    const int c0 = lane * 8;
    const int beg = rs[node], end = rs[node + 1];
    float a[8];
#pragma unroll
    for (int j = 0; j < 8; j++) a[j] = 0.f;
    int i = beg;
    for (; i + 4 <= end; i += 4) {
        int s[4];
        float w[4];
        uint4 hv[4];
#pragma unroll
        for (int u = 0; u < 4; u++) {
            s[u] = __builtin_nontemporal_load(csr + i + u);
            w[u] = __builtin_nontemporal_load(csr_w + i + u);
        }
#pragma unroll
        for (int u = 0; u < 4; u++) hv[u] = *(const uint4*)(hin + (size_t)s[u] * 512 + c0);
#pragma unroll
        for (int u = 0; u < 4; u++) {
            a[0] = fmaf(bf2f_lo(hv[u].x), w[u], a[0]);
            a[1] = fmaf(bf2f_hi(hv[u].x), w[u], a[1]);
            a[2] = fmaf(bf2f_lo(hv[u].y), w[u], a[2]);
            a[3] = fmaf(bf2f_hi(hv[u].y), w[u], a[3]);
            a[4] = fmaf(bf2f_lo(hv[u].z), w[u], a[4]);
            a[5] = fmaf(bf2f_hi(hv[u].z), w[u], a[5]);
            a[6] = fmaf(bf2f_lo(hv[u].w), w[u], a[6]);
            a[7] = fmaf(bf2f_hi(hv[u].w), w[u], a[7]);
        }
    }
    for (; i < end; i++) {
        const int sv = csr[i];
        const float w = csr_w[i];
        uint4 hv = *(const uint4*)(hin + (size_t)sv * 512 + c0);
        a[0] = fmaf(bf2f_lo(hv.x), w, a[0]);
        a[1] = fmaf(bf2f_hi(hv.x), w, a[1]);
        a[2] = fmaf(bf2f_lo(hv.y), w, a[2]);
        a[3] = fmaf(bf2f_hi(hv.y), w, a[3]);
        a[4] = fmaf(bf2f_lo(hv.z), w, a[4]);
        a[5] = fmaf(bf2f_hi(hv.z), w, a[5]);
        a[6] = fmaf(bf2f_lo(hv.w), w, a[6]);
        a[7] = fmaf(bf2f_hi(hv.w), w, a[7]);
    }
    {
        const float dn = dinv[node];
        const float ws = dn * dn;
        uint4 hv = *(const uint4*)(hin + (size_t)node * 512 + c0);
        a[0] = fmaf(bf2f_lo(hv.x), ws, a[0]);
        a[1] = fmaf(bf2f_hi(hv.x), ws, a[1]);
        a[2] = fmaf(bf2f_lo(hv.y), ws, a[2]);
        a[3] = fmaf(bf2f_hi(hv.y), ws, a[3]);
        a[4] = fmaf(bf2f_lo(hv.z), ws, a[4]);
        a[5] = fmaf(bf2f_hi(hv.z), ws, a[5]);
        a[6] = fmaf(bf2f_lo(hv.w), ws, a[6]);
        a[7] = fmaf(bf2f_hi(hv.w), ws, a[7]);
    }
    u32x4 ho, lo;
#pragma unroll
    for (int j = 0; j < 4; j++) {
        u16 h0 = f2bf(a[2 * j]), l0 = f2bf(a[2 * j] - bf2f(h0));
        u16 h1 = f2bf(a[2 * j + 1]), l1 = f2bf(a[2 * j + 1] - bf2f(h1));
        ho[j] = (unsigned)h0 | ((unsigned)h1 << 16);
        lo[j] = (unsigned)l0 | ((unsigned)l1 << 16);
    }
    __builtin_nontemporal_store(ho, (u32x4*)(oh + (size_t)node * 512 + c0));
    __builtin_nontemporal_store(lo, (u32x4*)(ol + (size_t)node * 512 + c0));
}

// ---------------- split-fp32 MFMA GEMM -------------------------------------
// OUTMODE: 0 = fp32 Cf, 1 = split pair Ch+Cl, 2 = bf16-only Ch.
template <int NFRAG, bool RELU, int OUTMODE>
__global__ __launch_bounds__(256, 2)
void gemm_mfma_kernel(const u16* __restrict__ Ah, const u16* __restrict__ Al,
                      const u16* __restrict__ Bth, const u16* __restrict__ Btl,
                      const float* __restrict__ bias,
                      float* __restrict__ Cf, u16* __restrict__ Ch, u16* __restrict__ Cl,
                      int M, int K, int Nn) {
    constexpr int BM = 128;
    constexpr int BN = NFRAG * 32;
    __shared__ u16 sAh[BM * 32], sAl[BM * 32], sBh[BN * 32], sBl[BN * 32];

    const int gx = gridDim.x;
    const int nwg = gx * gridDim.y;
    const int orig = blockIdx.y * gx + blockIdx.x;
    const int q8 = nwg >> 3, r8 = nwg & 7;
    const int xcd = orig & 7, lin = orig >> 3;
    const int wg = (xcd < r8 ? xcd * (q8 + 1) : r8 * (q8 + 1) + (xcd - r8) * q8) + lin;
    const int mt = wg / gx;
    const int nt = wg - mt * gx;
    const int m0 = mt * BM, n0 = nt * BN;

    const int tid = threadIdx.x;
    const int lane = tid & 63;
    const int wid = tid >> 6;
    const int wm = (wid >> 1) * 64;
    const int wn = (wid & 1) * (NFRAG * 16);

    const int row_b = tid >> 2;
    const int slot = tid & 3;
    const int sw0 = slot ^ ((row_b >> 1) & 3);
    const int lA0 = row_b * 32 + sw0 * 8;
    const int lA1 = lA0 + 64 * 32;
    const size_t gA0 = (size_t)(m0 + row_b) * K + slot * 8;
    const size_t gA1 = gA0 + (size_t)64 * K;
    const size_t gB0 = (size_t)(n0 + row_b) * K + slot * 8;
    const size_t gB1 = gB0 + (size_t)64 * K;

    int offA[4], offB[NFRAG];
    const int q = lane >> 4;
#pragma unroll
    for (int i = 0; i < 4; i++) {
        int r = wm + i * 16 + (lane & 15);
        offA[i] = r * 32 + ((q ^ ((r >> 1) & 3)) * 8);
    }
#pragma unroll
    for (int j = 0; j < NFRAG; j++) {
        int r = wn + j * 16 + (lane & 15);
        offB[j] = r * 32 + ((q ^ ((r >> 1) & 3)) * 8);
    }

    f32x4 acc[4][NFRAG];
#pragma unroll
    for (int i = 0; i < 4; i++)
#pragma unroll
        for (int j = 0; j < NFRAG; j++) acc[i][j] = (f32x4){0.f, 0.f, 0.f, 0.f};

    uint4 rA0h = *(const uint4*)(Ah + gA0);
    uint4 rA1h = *(const uint4*)(Ah + gA1);
    uint4 rA0l = *(const uint4*)(Al + gA0);
    uint4 rA1l = *(const uint4*)(Al + gA1);
    uint4 rB0h = *(const uint4*)(Bth + gB0);
    uint4 rB0l = *(const uint4*)(Btl + gB0);
    uint4 rB1h = {0, 0, 0, 0}, rB1l = {0, 0, 0, 0};
    if constexpr (NFRAG == 4) {
        rB1h = *(const uint4*)(Bth + gB1);
        rB1l = *(const uint4*)(Btl + gB1);
    }

    for (int k0 = 0; k0 < K; k0 += 32) {
        __syncthreads();
        *(uint4*)(sAh + lA0) = rA0h;
        *(uint4*)(sAh + lA1) = rA1h;
        *(uint4*)(sAl + lA0) = rA0l;
        *(uint4*)(sAl + lA1) = rA1l;
        *(uint4*)(sBh + lA0) = rB0h;
        *(uint4*)(sBl + lA0) = rB0l;
        if constexpr (NFRAG == 4) {
            *(uint4*)(sBh + lA1) = rB1h;
            *(uint4*)(sBl + lA1) = rB1l;
        }
        __syncthreads();

        if (k0 + 32 < K) {
            const int kn = k0 + 32;
            rA0h = *(const uint4*)(Ah + gA0 + kn);
            rA1h = *(const uint4*)(Ah + gA1 + kn);
            rA0l = *(const uint4*)(Al + gA0 + kn);
            rA1l = *(const uint4*)(Al + gA1 + kn);
            rB0h = *(const uint4*)(Bth + gB0 + kn);
            rB0l = *(const uint4*)(Btl + gB0 + kn);
            if constexpr (NFRAG == 4) {
                rB1h = *(const uint4*)(Bth + gB1 + kn);
                rB1l = *(const uint4*)(Btl + gB1 + kn);
            }
        }

        bf16x8 ah[4], al[4], bh[NFRAG], bl[NFRAG];
#pragma unroll
        for (int i = 0; i < 4; i++) {
            ah[i] = *(const bf16x8*)(sAh + offA[i]);
            al[i] = *(const bf16x8*)(sAl + offA[i]);
        }
#pragma unroll
        for (int j = 0; j < NFRAG; j++) {
            bh[j] = *(const bf16x8*)(sBh + offB[j]);
            bl[j] = *(const bf16x8*)(sBl + offB[j]);
        }
#pragma unroll
        for (int i = 0; i < 4; i++)
#pragma unroll
            for (int j = 0; j < NFRAG; j++) {
                acc[i][j] = __builtin_amdgcn_mfma_f32_16x16x32_bf16(ah[i], bh[j], acc[i][j], 0, 0, 0);
                acc[i][j] = __builtin_amdgcn_mfma_f32_16x16x32_bf16(ah[i], bl[j], acc[i][j], 0, 0, 0);
                acc[i][j] = __builtin_amdgcn_mfma_f32_16x16x32_bf16(al[i], bh[j], acc[i][j], 0, 0, 0);
            }
    }

    const int cn = lane & 15;
    const int cm = (lane >> 4) * 4;
#pragma unroll
    for (int i = 0; i < 4; i++) {
#pragma unroll
        for (int j = 0; j < NFRAG; j++) {
            const int col = n0 + wn + j * 16 + cn;
            const float bv = bias[col];
#pragma unroll
            for (int r = 0; r < 4; r++) {
                const int row = m0 + wm + i * 16 + cm + r;
                if (row < M) {
                    float v = acc[i][j][r] + bv;
                    if (RELU) v = fmaxf(v, 0.f);
                    if constexpr (OUTMODE == 1) {
                        u16 h = f2bf(v);
                        u16 l = f2bf(v - bf2f(h));
                        Ch[(size_t)row * Nn + col] = h;
                        Cl[(size_t)row * Nn + col] = l;
                    } else if constexpr (OUTMODE == 2) {
                        Ch[(size_t)row * Nn + col] = f2bf(v);
                    } else {
                        Cf[(size_t)row * Nn + col] = v;
                    }
                }
            }
        }
    }
}

// ---------------------------------------------------------------------------
extern "C" void kernel_launch(void* const* d_in, const int* in_sizes, int n_in,
                              void* d_out, int out_size, void* d_ws, size_t ws_size,
                              hipStream_t stream) {
    const float* x  = (const float*)d_in[0];
    const int*   ei = (const int*)d_in[1];
    const float* W1 = (const float*)d_in[2];
    const float* b1 = (const float*)d_in[3];
    const float* W2 = (const float*)d_in[4];
    const float* b2 = (const float*)d_in[5];
    const float* Wl = (const float*)d_in[6];
    const float* bl = (const float*)d_in[7];
    float* out = (float*)d_out;

    const int N = in_sizes[0] / 256;  // 50000
    const int E = in_sizes[1] / 2;    // 800000
    const int Mpad = ((N + 127) / 128) * 128;  // 50048
    const int* src = ei;
    const int* dst = ei + E;

    size_t off = 0;
    auto alloc = [&](size_t bytes) -> void* {
        void* p = (char*)d_ws + off;
        off += (bytes + 255) & ~(size_t)255;
        return p;
    };
    float* deg       = (float*)alloc((size_t)N * 4);
    float* dinv      = (float*)alloc((size_t)N * 4);
    int*   row_start = (int*)alloc((size_t)(N + 1) * 4);
    int*   cursor    = (int*)alloc((size_t)N * 4);
    int*   csr       = (int*)alloc((size_t)E * 4);
    float* csr_w     = (float*)alloc((size_t)E * 4);
    u16*   xh        = (u16*)alloc((size_t)N * 256 * 2);
    u16*   bt1h = (u16*)alloc((size_t)512 * 256 * 2);
    u16*   bt1l = (u16*)alloc((size_t)512 * 256 * 2);
    u16*   bt2h = (u16*)alloc((size_t)512 * 512 * 2);
    u16*   bt2l = (u16*)alloc((size_t)512 * 512 * 2);
    u16*   bt3h = (u16*)alloc((size_t)64 * 512 * 2);
    u16*   bt3l = (u16*)alloc((size_t)64 * 512 * 2);
    u16*   slabA = (u16*)alloc((size_t)Mpad * 512 * 2 * 2);
    u16*   slabH = (u16*)alloc((size_t)Mpad * 512 * 2 * 2);
    (void)ws_size;

    u16* a1h = slabA;                              // [Mpad,256] pair, agg1->gemm1
    u16* a1l = slabA + (size_t)Mpad * 256;
    u16* a2h = slabA;                              // [Mpad,512] pair, agg2->gemm2
    u16* a2l = slabA + (size_t)Mpad * 512;
    u16* h1h = slabH;                              // [Mpad,512] bf16-only, gemm1->agg2
    u16* h2h = slabH;                              // [Mpad,512] pair, gemm2->gemm3
    u16* h2l = slabH + (size_t)Mpad * 512;

    init_deg_kernel<<<(N + 255) / 256, 256, 0, stream>>>(deg, N);
    count_deg_kernel<<<(E + 255) / 256, 256, 0, stream>>>(dst, deg, E);
    scan_kernel<<<1, 1024, 0, stream>>>(deg, dinv, row_start, cursor, N);
    bucket_kernel<<<(E + 255) / 256, 256, 0, stream>>>(src, dst, row_start, cursor, csr, csr_w, dinv, E);

    wsplit_kernel<<<(512 * 32 + 255) / 256, 256, 0, stream>>>(W1, bt1h, bt1l, 256, 512);
    wsplit_kernel<<<(512 * 64 + 255) / 256, 256, 0, stream>>>(W2, bt2h, bt2l, 512, 512);
    wsplit_kernel<<<(64 * 64 + 255) / 256, 256, 0, stream>>>(Wl, bt3h, bt3l, 512, 64);
    xsplit_kernel<<<((N * 32) + 255) / 256, 256, 0, stream>>>(x, xh, (size_t)N * 32);

    // layer 1
    agg_x_kernel<<<(N + 3) / 4, 256, 0, stream>>>(x, xh, a1h, a1l, csr, csr_w, row_start, dinv, N);
    gemm_mfma_kernel<4, true, 2><<<dim3(4, Mpad / 128), 256, 0, stream>>>(
        a1h, a1l, bt1h, bt1l, b1, nullptr, h1h, nullptr, N, 256, 512);

    // layer 2
    agg_h_kernel<<<(N + 3) / 4, 256, 0, stream>>>(h1h, a2h, a2l, csr, csr_w, row_start, dinv, N);
    gemm_mfma_kernel<4, true, 1><<<dim3(4, Mpad / 128), 256, 0, stream>>>(
        a2h, a2l, bt2h, bt2l, b2, nullptr, h2h, h2l, N, 512, 512);

    // output projection
    gemm_mfma_kernel<2, false, 0><<<dim3(1, Mpad / 128), 256, 0, stream>>>(
        h2h, h2l, bt3h, bt3l, bl, out, nullptr, nullptr, N, 512, 64);
}

// Round 6
// 613.556 us; speedup vs baseline: 1.9302x; 1.0414x over previous
//
#include <hip/hip_runtime.h>
#include <cstdint>
#include <cstddef>

typedef unsigned short u16;
typedef __attribute__((ext_vector_type(8))) _Float16 f16x8;
typedef __attribute__((ext_vector_type(4))) float f32x4;
typedef __attribute__((ext_vector_type(2))) unsigned u32x2;
typedef __attribute__((ext_vector_type(4))) unsigned u32x4;

// ---------------- fp16 helpers ---------------------------------------------
__device__ __forceinline__ u16 f2h(float f) {
    _Float16 h = (_Float16)f;
    union { _Float16 h; u16 u; } v; v.h = h;
    return v.u;
}
__device__ __forceinline__ float h2f(u16 b) {
    union { u16 u; _Float16 h; } v; v.u = b;
    return (float)v.h;
}
__device__ __forceinline__ float h2f_lo(unsigned w) { return h2f((u16)(w & 0xFFFFu)); }
__device__ __forceinline__ float h2f_hi(unsigned w) { return h2f((u16)(w >> 16)); }

// async global->LDS 16B per lane: lds dest = wave-uniform base + lane*16
__device__ __forceinline__ void gload16(const u16* g, u16* l) {
    __builtin_amdgcn_global_load_lds(
        (const __attribute__((address_space(1))) void*)g,
        (__attribute__((address_space(3))) void*)l, 16, 0, 0);
}

// ---------------- graph setup ----------------------------------------------
__global__ void init_deg_kernel(float* __restrict__ deg, int n) {
    int i = blockIdx.x * blockDim.x + threadIdx.x;
    if (i < n) deg[i] = 1.0f;  // self-loop
}

__global__ void count_deg_kernel(const int* __restrict__ dst, float* __restrict__ deg, int e) {
    int i = blockIdx.x * blockDim.x + threadIdx.x;
    if (i < e) atomicAdd(&deg[dst[i]], 1.0f);  // integer-valued fp32: exact, order-independent
}

__global__ __launch_bounds__(1024)
void scan_kernel(const float* __restrict__ deg, float* __restrict__ dinv,
                 int* __restrict__ row_start, int* __restrict__ cursor, int n) {
    __shared__ int sm[1024];
    __shared__ int carry_s;
    const int t = threadIdx.x;
    if (t == 0) carry_s = 0;
    __syncthreads();
    for (int base = 0; base < n; base += 1024) {
        int i = base + t;
        int v = 0;
        if (i < n) {
            float d = deg[i];
            dinv[i] = rsqrtf(d);
            cursor[i] = 0;
            v = (int)d - 1;
        }
        sm[t] = v;
        __syncthreads();
        int carry = carry_s;
        for (int off = 1; off < 1024; off <<= 1) {
            int tv = (t >= off) ? sm[t - off] : 0;
            __syncthreads();
            sm[t] += tv;
            __syncthreads();
        }
        if (i < n) row_start[i] = carry + sm[t] - v;
        if (t == 1023) carry_s = carry + sm[1023];
        __syncthreads();
    }
    if (t == 0) row_start[n] = carry_s;
}

__global__ void bucket_kernel(const int* __restrict__ src, const int* __restrict__ dst,
                              const int* __restrict__ row_start, int* __restrict__ cursor,
                              int* __restrict__ csr, float* __restrict__ csr_w,
                              const float* __restrict__ dinv, int e) {
    int i = blockIdx.x * blockDim.x + threadIdx.x;
    if (i < e) {
        int d = dst[i];
        int s = src[i];
        int pos = atomicAdd(&cursor[d], 1);
        int at = row_start[d] + pos;
        csr[at] = s;
        csr_w[at] = dinv[s] * dinv[d];
    }
}

// ---------------- weight transpose: W[K,N] -> Bt[N,K] fp16 -----------------
__global__ void wtrans_kernel(const float* __restrict__ W, u16* __restrict__ bt, int K, int N) {
    const int k8 = K >> 3;
    const int idx = blockIdx.x * blockDim.x + threadIdx.x;
    if (idx >= N * k8) return;
    const int n = idx / k8;
    const int k0 = (idx - n * k8) * 8;
    alignas(16) u16 h8[8];
#pragma unroll
    for (int j = 0; j < 8; j++) h8[j] = f2h(W[(size_t)(k0 + j) * N + n]);
    *(uint4*)(bt + (size_t)n * K + k0) = *(const uint4*)h8;
}

// ---------------- x -> fp16 copy (gather-side compression) -----------------
__global__ void xsplit_kernel(const float* __restrict__ x, u16* __restrict__ xh, size_t total8) {
    const size_t idx = (size_t)blockIdx.x * blockDim.x + threadIdx.x;
    if (idx >= total8) return;
    const float4 v0 = *(const float4*)(x + idx * 8);
    const float4 v1 = *(const float4*)(x + idx * 8 + 4);
    alignas(16) u16 h8[8];
    h8[0] = f2h(v0.x); h8[1] = f2h(v0.y); h8[2] = f2h(v0.z); h8[3] = f2h(v0.w);
    h8[4] = f2h(v1.x); h8[5] = f2h(v1.y); h8[6] = f2h(v1.z); h8[7] = f2h(v1.w);
    *(uint4*)(xh + idx * 8) = *(const uint4*)h8;
}

// ---------------- layer-1 aggregation (x fp16 gather, F=256) ---------------
__global__ __launch_bounds__(256)
void agg_x_kernel(const float* __restrict__ x, const u16* __restrict__ xh,
                  u16* __restrict__ oh, u16* __restrict__ ol,
                  const int* __restrict__ csr, const float* __restrict__ csr_w,
                  const int* __restrict__ rs, const float* __restrict__ dinv, int n) {
    const int node = blockIdx.x * 4 + (threadIdx.x >> 6);
    if (node >= n) return;
    const int lane = threadIdx.x & 63;
    const int c0 = lane * 4;
    const int beg = rs[node], end = rs[node + 1];
    float a0 = 0.f, a1 = 0.f, a2 = 0.f, a3 = 0.f;
    int i = beg;
    for (; i + 4 <= end; i += 4) {
        int s[4];
        float w[4];
        uint2 hv[4];
#pragma unroll
        for (int u = 0; u < 4; u++) {
            s[u] = __builtin_nontemporal_load(csr + i + u);
            w[u] = __builtin_nontemporal_load(csr_w + i + u);
        }
#pragma unroll
        for (int u = 0; u < 4; u++) hv[u] = *(const uint2*)(xh + (size_t)s[u] * 256 + c0);
#pragma unroll
        for (int u = 0; u < 4; u++) {
            a0 = fmaf(h2f_lo(hv[u].x), w[u], a0);
            a1 = fmaf(h2f_hi(hv[u].x), w[u], a1);
            a2 = fmaf(h2f_lo(hv[u].y), w[u], a2);
            a3 = fmaf(h2f_hi(hv[u].y), w[u], a3);
        }
    }
    for (; i < end; i++) {
        const int sv = csr[i];
        const float w = csr_w[i];
        uint2 hv = *(const uint2*)(xh + (size_t)sv * 256 + c0);
        a0 = fmaf(h2f_lo(hv.x), w, a0);
        a1 = fmaf(h2f_hi(hv.x), w, a1);
        a2 = fmaf(h2f_lo(hv.y), w, a2);
        a3 = fmaf(h2f_hi(hv.y), w, a3);
    }
    {
        const float dn = dinv[node];
        const float ws = dn * dn;
        const float4 xv = *(const float4*)(x + (size_t)node * 256 + c0);
        a0 = fmaf(xv.x, ws, a0);
        a1 = fmaf(xv.y, ws, a1);
        a2 = fmaf(xv.z, ws, a2);
        a3 = fmaf(xv.w, ws, a3);
    }
    u16 h0 = f2h(a0), l0 = f2h(a0 - h2f(h0));
    u16 h1 = f2h(a1), l1 = f2h(a1 - h2f(h1));
    u16 h2 = f2h(a2), l2 = f2h(a2 - h2f(h2));
    u16 h3 = f2h(a3), l3 = f2h(a3 - h2f(h3));
    u32x2 ho, lo;
    ho.x = (unsigned)h0 | ((unsigned)h1 << 16);
    ho.y = (unsigned)h2 | ((unsigned)h3 << 16);
    lo.x = (unsigned)l0 | ((unsigned)l1 << 16);
    lo.y = (unsigned)l2 | ((unsigned)l3 << 16);
    __builtin_nontemporal_store(ho, (u32x2*)(oh + (size_t)node * 256 + c0));
    __builtin_nontemporal_store(lo, (u32x2*)(ol + (size_t)node * 256 + c0));
}

// ---------------- layer-2 aggregation (h1 fp16 gather, F=512) --------------
__global__ __launch_bounds__(256)
void agg_h_kernel(const u16* __restrict__ hin,
                  u16* __restrict__ oh, u16* __restrict__ ol,
                  const int* __restrict__ csr, const float* __restrict__ csr_w,
                  const int* __restrict__ rs, const float* __restrict__ dinv, int n) {
    const int node = blockIdx.x * 4 + (threadIdx.x >> 6);
    if (node >= n) return;
    const int lane = threadIdx.x & 63;
    const int c0 = lane * 8;
    const int beg = rs[node], end = rs[node + 1];
    float a[8];
#pragma unroll
    for (int j = 0; j < 8; j++) a[j] = 0.f;
    int i = beg;
    for (; i + 4 <= end; i += 4) {
        int s[4];
        float w[4];
        uint4 hv[4];
#pragma unroll
        for (int u = 0; u < 4; u++) {
            s[u] = __builtin_nontemporal_load(csr + i + u);
            w[u] = __builtin_nontemporal_load(csr_w + i + u);
        }
#pragma unroll
        for (int u = 0; u < 4; u++) hv[u] = *(const uint4*)(hin + (size_t)s[u] * 512 + c0);
#pragma unroll
        for (int u = 0; u < 4; u++) {
            a[0] = fmaf(h2f_lo(hv[u].x), w[u], a[0]);
            a[1] = fmaf(h2f_hi(hv[u].x), w[u], a[1]);
            a[2] = fmaf(h2f_lo(hv[u].y), w[u], a[2]);
            a[3] = fmaf(h2f_hi(hv[u].y), w[u], a[3]);
            a[4] = fmaf(h2f_lo(hv[u].z), w[u], a[4]);
            a[5] = fmaf(h2f_hi(hv[u].z), w[u], a[5]);
            a[6] = fmaf(h2f_lo(hv[u].w), w[u], a[6]);
            a[7] = fmaf(h2f_hi(hv[u].w), w[u], a[7]);
        }
    }
    for (; i < end; i++) {
        const int sv = csr[i];
        const float w = csr_w[i];
        uint4 hv = *(const uint4*)(hin + (size_t)sv * 512 + c0);
        a[0] = fmaf(h2f_lo(hv.x), w, a[0]);
        a[1] = fmaf(h2f_hi(hv.x), w, a[1]);
        a[2] = fmaf(h2f_lo(hv.y), w, a[2]);
        a[3] = fmaf(h2f_hi(hv.y), w, a[3]);
        a[4] = fmaf(h2f_lo(hv.z), w, a[4]);
        a[5] = fmaf(h2f_hi(hv.z), w, a[5]);
        a[6] = fmaf(h2f_lo(hv.w), w, a[6]);
        a[7] = fmaf(h2f_hi(hv.w), w, a[7]);
    }
    {
        const float dn = dinv[node];
        const float ws = dn * dn;
        uint4 hv = *(const uint4*)(hin + (size_t)node * 512 + c0);
        a[0] = fmaf(h2f_lo(hv.x), ws, a[0]);
        a[1] = fmaf(h2f_hi(hv.x), ws, a[1]);
        a[2] = fmaf(h2f_lo(hv.y), ws, a[2]);
        a[3] = fmaf(h2f_hi(hv.y), ws, a[3]);
        a[4] = fmaf(h2f_lo(hv.z), ws, a[4]);
        a[5] = fmaf(h2f_hi(hv.z), ws, a[5]);
        a[6] = fmaf(h2f_lo(hv.w), ws, a[6]);
        a[7] = fmaf(h2f_hi(hv.w), ws, a[7]);
    }
    u32x4 ho, lo;
#pragma unroll
    for (int j = 0; j < 4; j++) {
        u16 h0 = f2h(a[2 * j]), l0 = f2h(a[2 * j] - h2f(h0));
        u16 h1 = f2h(a[2 * j + 1]), l1 = f2h(a[2 * j + 1] - h2f(h1));
        ho[j] = (unsigned)h0 | ((unsigned)h1 << 16);
        lo[j] = (unsigned)l0 | ((unsigned)l1 << 16);
    }
    __builtin_nontemporal_store(ho, (u32x4*)(oh + (size_t)node * 512 + c0));
    __builtin_nontemporal_store(lo, (u32x4*)(ol + (size_t)node * 512 + c0));
}

// ---------------- split-fp32 MFMA GEMM (fp16, 2-term) ----------------------
// C[M,Nn] = (Ah+Al)[M,K] @ Bt[Nn,K]^T, all fp16. 2 MFMAs per tile product.
// BM=128, BN=NFRAG*32, BK=32. 4 waves 2x2. global_load_lds staging with
// pre-swizzled global source (slot' = slot ^ ((row>>1)&3), LDS linear).
// OUTMODE: 0 = fp32 Cf, 1 = fp16 pair Ch+Cl, 2 = fp16 single Ch.
template <int NFRAG, bool RELU, int OUTMODE>
__global__ __launch_bounds__(256)
void gemm_mfma_kernel(const u16* __restrict__ Ah, const u16* __restrict__ Al,
                      const u16* __restrict__ Bt,
                      const float* __restrict__ bias,
                      float* __restrict__ Cf, u16* __restrict__ Ch, u16* __restrict__ Cl,
                      int M, int K, int Nn) {
    constexpr int BM = 128;
    constexpr int BN = NFRAG * 32;
    constexpr int NROUND = 4 + NFRAG / 2;  // Ah:2, Al:2, B: NFRAG/2
    __shared__ u16 sAh[BM * 32], sAl[BM * 32], sB[BN * 32];

    // bijective XCD swizzle (m204)
    const int gx = gridDim.x;
    const int nwg = gx * gridDim.y;
    const int orig = blockIdx.y * gx + blockIdx.x;
    const int q8 = nwg >> 3, r8 = nwg & 7;
    const int xcd = orig & 7, lin = orig >> 3;
    const int wg = (xcd < r8 ? xcd * (q8 + 1) : r8 * (q8 + 1) + (xcd - r8) * q8) + lin;
    const int mt = wg / gx;
    const int nt = wg - mt * gx;
    const int m0 = mt * BM, n0 = nt * BN;

    const int tid = threadIdx.x;
    const int lane = tid & 63;
    const int wid = tid >> 6;
    const int wm = (wid >> 1) * 64;
    const int wn = (wid & 1) * (NFRAG * 16);

    // staging: per round, 256 threads cover 64 rows x 4 slots (16B chunks).
    // LDS linear; global source slot pre-swizzled.
    const int srow = tid >> 2;                          // in-round row 0..63
    const int gslot = (tid & 3) ^ ((tid >> 3) & 3);     // inverse swizzle
    const int lbase = (wid * 16) * 32;                  // wave-uniform, u16 units

    // per-round global row pointers (element offsets added at issue)
    const u16* gA0 = Ah + (size_t)(m0 + srow) * K + gslot * 8;
    const u16* gA1 = Ah + (size_t)(m0 + 64 + srow) * K + gslot * 8;
    const u16* gL0 = Al + (size_t)(m0 + srow) * K + gslot * 8;
    const u16* gL1 = Al + (size_t)(m0 + 64 + srow) * K + gslot * 8;
    const u16* gB0 = Bt + (size_t)(n0 + srow) * K + gslot * 8;
    const u16* gB1 = Bt + (size_t)(n0 + 64 + srow) * K + gslot * 8;  // NFRAG==4 only

    // fragment LDS read offsets (u16 units)
    int offA[4], offB[NFRAG];
    const int q = lane >> 4;
#pragma unroll
    for (int i = 0; i < 4; i++) {
        int r = wm + i * 16 + (lane & 15);
        offA[i] = r * 32 + ((q ^ ((r >> 1) & 3)) * 8);
    }
#pragma unroll
    for (int j = 0; j < NFRAG; j++) {
        int r = wn + j * 16 + (lane & 15);
        offB[j] = r * 32 + ((q ^ ((r >> 1) & 3)) * 8);
    }

    f32x4 acc[4][NFRAG];
#pragma unroll
    for (int i = 0; i < 4; i++)
#pragma unroll
        for (int j = 0; j < NFRAG; j++) acc[i][j] = (f32x4){0.f, 0.f, 0.f, 0.f};

    auto stage = [&](int k0) {
        gload16(gA0 + k0, sAh + lbase);
        gload16(gA1 + k0, sAh + 64 * 32 + lbase);
        gload16(gL0 + k0, sAl + lbase);
        gload16(gL1 + k0, sAl + 64 * 32 + lbase);
        gload16(gB0 + k0, sB + lbase);
        if constexpr (NFRAG == 4) gload16(gB1 + k0, sB + 64 * 32 + lbase);
    };

    stage(0);
    for (int k0 = 0; k0 < K; k0 += 32) {
        __syncthreads();  // drains vmcnt -> staged tile visible

        f16x8 ah[4], al[4], b[NFRAG];
#pragma unroll
        for (int i = 0; i < 4; i++) {
            ah[i] = *(const f16x8*)(sAh + offA[i]);
            al[i] = *(const f16x8*)(sAl + offA[i]);
        }
#pragma unroll
        for (int j = 0; j < NFRAG; j++) b[j] = *(const f16x8*)(sB + offB[j]);

#pragma unroll
        for (int i = 0; i < 4; i++)
#pragma unroll
            for (int j = 0; j < NFRAG; j++) {
                acc[i][j] = __builtin_amdgcn_mfma_f32_16x16x32_f16(ah[i], b[j], acc[i][j], 0, 0, 0);
                acc[i][j] = __builtin_amdgcn_mfma_f32_16x16x32_f16(al[i], b[j], acc[i][j], 0, 0, 0);
            }

        __syncthreads();  // all waves done reading LDS
        if (k0 + 32 < K) stage(k0 + 32);
    }

    // epilogue: C row = wm + i*16 + (lane>>4)*4 + r, col = wn + j*16 + (lane&15)
    const int cn = lane & 15;
    const int cm = (lane >> 4) * 4;
#pragma unroll
    for (int i = 0; i < 4; i++) {
#pragma unroll
        for (int j = 0; j < NFRAG; j++) {
            const int col = n0 + wn + j * 16 + cn;
            const float bv = bias[col];
#pragma unroll
            for (int r = 0; r < 4; r++) {
                const int row = m0 + wm + i * 16 + cm + r;
                if (row < M) {
                    float v = acc[i][j][r] + bv;
                    if (RELU) v = fmaxf(v, 0.f);
                    if constexpr (OUTMODE == 1) {
                        u16 h = f2h(v);
                        Ch[(size_t)row * Nn + col] = h;
                        Cl[(size_t)row * Nn + col] = f2h(v - h2f(h));
                    } else if constexpr (OUTMODE == 2) {
                        Ch[(size_t)row * Nn + col] = f2h(v);
                    } else {
                        Cf[(size_t)row * Nn + col] = v;
                    }
                }
            }
        }
    }
}

// ---------------------------------------------------------------------------
extern "C" void kernel_launch(void* const* d_in, const int* in_sizes, int n_in,
                              void* d_out, int out_size, void* d_ws, size_t ws_size,
                              hipStream_t stream) {
    const float* x  = (const float*)d_in[0];
    const int*   ei = (const int*)d_in[1];
    const float* W1 = (const float*)d_in[2];
    const float* b1 = (const float*)d_in[3];
    const float* W2 = (const float*)d_in[4];
    const float* b2 = (const float*)d_in[5];
    const float* Wl = (const float*)d_in[6];
    const float* bl = (const float*)d_in[7];
    float* out = (float*)d_out;

    const int N = in_sizes[0] / 256;  // 50000
    const int E = in_sizes[1] / 2;    // 800000
    const int Mpad = ((N + 127) / 128) * 128;  // 50048
    const int* src = ei;
    const int* dst = ei + E;

    size_t off = 0;
    auto alloc = [&](size_t bytes) -> void* {
        void* p = (char*)d_ws + off;
        off += (bytes + 255) & ~(size_t)255;
        return p;
    };
    float* deg       = (float*)alloc((size_t)N * 4);
    float* dinv      = (float*)alloc((size_t)N * 4);
    int*   row_start = (int*)alloc((size_t)(N + 1) * 4);
    int*   cursor    = (int*)alloc((size_t)N * 4);
    int*   csr       = (int*)alloc((size_t)E * 4);
    float* csr_w     = (float*)alloc((size_t)E * 4);
    u16*   xh        = (u16*)alloc((size_t)N * 256 * 2);
    u16*   bt1 = (u16*)alloc((size_t)512 * 256 * 2);
    u16*   bt2 = (u16*)alloc((size_t)512 * 512 * 2);
    u16*   bt3 = (u16*)alloc((size_t)64 * 512 * 2);
    u16*   slabA = (u16*)alloc((size_t)Mpad * 512 * 2 * 2);
    u16*   slabH = (u16*)alloc((size_t)Mpad * 512 * 2 * 2);
    (void)ws_size;

    u16* a1h = slabA;                              // [Mpad,256] pair, agg1->gemm1
    u16* a1l = slabA + (size_t)Mpad * 256;
    u16* a2h = slabA;                              // [Mpad,512] pair, agg2->gemm2
    u16* a2l = slabA + (size_t)Mpad * 512;
    u16* h1h = slabH;                              // [Mpad,512] fp16 single, gemm1->agg2
    u16* h2h = slabH;                              // [Mpad,512] pair, gemm2->gemm3
    u16* h2l = slabH + (size_t)Mpad * 512;

    init_deg_kernel<<<(N + 255) / 256, 256, 0, stream>>>(deg, N);
    count_deg_kernel<<<(E + 255) / 256, 256, 0, stream>>>(dst, deg, E);
    scan_kernel<<<1, 1024, 0, stream>>>(deg, dinv, row_start, cursor, N);
    bucket_kernel<<<(E + 255) / 256, 256, 0, stream>>>(src, dst, row_start, cursor, csr, csr_w, dinv, E);

    wtrans_kernel<<<(512 * 32 + 255) / 256, 256, 0, stream>>>(W1, bt1, 256, 512);
    wtrans_kernel<<<(512 * 64 + 255) / 256, 256, 0, stream>>>(W2, bt2, 512, 512);
    wtrans_kernel<<<(64 * 64 + 255) / 256, 256, 0, stream>>>(Wl, bt3, 512, 64);
    xsplit_kernel<<<((N * 32) + 255) / 256, 256, 0, stream>>>(x, xh, (size_t)N * 32);

    // layer 1
    agg_x_kernel<<<(N + 3) / 4, 256, 0, stream>>>(x, xh, a1h, a1l, csr, csr_w, row_start, dinv, N);
    gemm_mfma_kernel<4, true, 2><<<dim3(4, Mpad / 128), 256, 0, stream>>>(
        a1h, a1l, bt1, b1, nullptr, h1h, nullptr, N, 256, 512);

    // layer 2
    agg_h_kernel<<<(N + 3) / 4, 256, 0, stream>>>(h1h, a2h, a2l, csr, csr_w, row_start, dinv, N);
    gemm_mfma_kernel<4, true, 1><<<dim3(4, Mpad / 128), 256, 0, stream>>>(
        a2h, a2l, bt2, b2, nullptr, h2h, h2l, N, 512, 512);

    // output projection
    gemm_mfma_kernel<2, false, 0><<<dim3(1, Mpad / 128), 256, 0, stream>>>(
        h2h, h2l, bt3, bl, out, nullptr, nullptr, N, 512, 64);
}

// Round 7
// 441.112 us; speedup vs baseline: 2.6848x; 1.3909x over previous
//
#include <hip/hip_runtime.h>
#include <cstdint>
#include <cstddef>

typedef unsigned short u16;
typedef __attribute__((ext_vector_type(8))) _Float16 f16x8;
typedef __attribute__((ext_vector_type(4))) float f32x4;
typedef __attribute__((ext_vector_type(2))) unsigned u32x2;
typedef __attribute__((ext_vector_type(4))) unsigned u32x4;

// ---------------- fp16 helpers ---------------------------------------------
__device__ __forceinline__ u16 f2h(float f) {
    union { _Float16 h; u16 u; } v; v.h = (_Float16)f;
    return v.u;
}
__device__ __forceinline__ float h2f(u16 b) {
    union { u16 u; _Float16 h; } v; v.u = b;
    return (float)v.h;
}
__device__ __forceinline__ float h2f_lo(unsigned w) { return h2f((u16)(w & 0xFFFFu)); }
__device__ __forceinline__ float h2f_hi(unsigned w) { return h2f((u16)(w >> 16)); }

__device__ __forceinline__ void gload16(const u16* g, u16* l) {
    __builtin_amdgcn_global_load_lds(
        (const __attribute__((address_space(1))) void*)g,
        (__attribute__((address_space(3))) void*)l, 16, 0, 0);
}

// ---------------- graph setup ----------------------------------------------
__global__ void init_deg_kernel(float* __restrict__ deg, int n) {
    int i = blockIdx.x * blockDim.x + threadIdx.x;
    if (i < n) deg[i] = 1.0f;  // self-loop
}

__global__ void count_deg_kernel(const int* __restrict__ dst, float* __restrict__ deg, int e) {
    int i = blockIdx.x * blockDim.x + threadIdx.x;
    if (i < e) atomicAdd(&deg[dst[i]], 1.0f);  // integer-valued fp32: exact, order-independent
}

// ---- 3-kernel parallel exclusive scan of (deg-1) ----
__global__ __launch_bounds__(1024)
void scan1_kernel(const float* __restrict__ deg, int* __restrict__ part, int n) {
    __shared__ int sm[1024];
    const int t = threadIdx.x;
    const int i = blockIdx.x * 1024 + t;
    sm[t] = (i < n) ? (int)deg[i] - 1 : 0;
    __syncthreads();
    for (int off = 512; off > 0; off >>= 1) {
        if (t < off) sm[t] += sm[t + off];
        __syncthreads();
    }
    if (t == 0) part[blockIdx.x] = sm[0];
}

__global__ __launch_bounds__(1024)
void scan2_kernel(int* __restrict__ part, int nb) {
    __shared__ int sm[1024];
    const int t = threadIdx.x;
    const int v = (t < nb) ? part[t] : 0;
    sm[t] = v;
    __syncthreads();
    for (int off = 1; off < 1024; off <<= 1) {
        int tv = (t >= off) ? sm[t - off] : 0;
        __syncthreads();
        sm[t] += tv;
        __syncthreads();
    }
    if (t < nb) part[t] = sm[t] - v;  // exclusive
}

__global__ __launch_bounds__(1024)
void scan3_kernel(const float* __restrict__ deg, const int* __restrict__ part,
                  float* __restrict__ dinv, int* __restrict__ row_start,
                  int* __restrict__ cursor, int n) {
    __shared__ int sm[1024];
    const int t = threadIdx.x;
    const int b = blockIdx.x;
    const int i = b * 1024 + t;
    int v = 0;
    float d = 1.f;
    if (i < n) {
        d = deg[i];
        v = (int)d - 1;
    }
    sm[t] = v;
    __syncthreads();
    for (int off = 1; off < 1024; off <<= 1) {
        int tv = (t >= off) ? sm[t - off] : 0;
        __syncthreads();
        sm[t] += tv;
        __syncthreads();
    }
    if (i < n) {
        row_start[i] = part[b] + sm[t] - v;
        dinv[i] = rsqrtf(d);
        cursor[i] = 0;
    }
    if (i == n - 1) row_start[n] = part[b] + sm[t];
}

__global__ void bucket_kernel(const int* __restrict__ src, const int* __restrict__ dst,
                              const int* __restrict__ row_start, int* __restrict__ cursor,
                              int* __restrict__ csr, float* __restrict__ csr_w,
                              const float* __restrict__ dinv, int e) {
    int i = blockIdx.x * blockDim.x + threadIdx.x;
    if (i < e) {
        int d = dst[i];
        int s = src[i];
        int pos = atomicAdd(&cursor[d], 1);
        int at = row_start[d] + pos;
        csr[at] = s;
        csr_w[at] = dinv[s] * dinv[d];
    }
}

// ---------------- weight transpose: W[K,N] -> Bt[N,K] fp16 -----------------
__global__ void wtrans_kernel(const float* __restrict__ W, u16* __restrict__ bt, int K, int N) {
    const int k8 = K >> 3;
    const int idx = blockIdx.x * blockDim.x + threadIdx.x;
    if (idx >= N * k8) return;
    const int n = idx / k8;
    const int k0 = (idx - n * k8) * 8;
    alignas(16) u16 h8[8];
#pragma unroll
    for (int j = 0; j < 8; j++) h8[j] = f2h(W[(size_t)(k0 + j) * N + n]);
    *(uint4*)(bt + (size_t)n * K + k0) = *(const uint4*)h8;
}

// ---------------- x -> fp16 copy -------------------------------------------
__global__ void xsplit_kernel(const float* __restrict__ x, u16* __restrict__ xh, size_t total8) {
    const size_t idx = (size_t)blockIdx.x * blockDim.x + threadIdx.x;
    if (idx >= total8) return;
    const float4 v0 = *(const float4*)(x + idx * 8);
    const float4 v1 = *(const float4*)(x + idx * 8 + 4);
    alignas(16) u16 h8[8];
    h8[0] = f2h(v0.x); h8[1] = f2h(v0.y); h8[2] = f2h(v0.z); h8[3] = f2h(v0.w);
    h8[4] = f2h(v1.x); h8[5] = f2h(v1.y); h8[6] = f2h(v1.z); h8[7] = f2h(v1.w);
    *(uint4*)(xh + idx * 8) = *(const uint4*)h8;
}

// ---------------- layer-1 aggregation (x fp16 gather, F=256) ---------------
__global__ __launch_bounds__(256)
void agg_x_kernel(const float* __restrict__ x, const u16* __restrict__ xh,
                  u16* __restrict__ oh,
                  const int* __restrict__ csr, const float* __restrict__ csr_w,
                  const int* __restrict__ rs, const float* __restrict__ dinv, int n) {
    const int node = blockIdx.x * 4 + (threadIdx.x >> 6);
    if (node >= n) return;
    const int lane = threadIdx.x & 63;
    const int c0 = lane * 4;
    const int beg = rs[node], end = rs[node + 1];
    float a0 = 0.f, a1 = 0.f, a2 = 0.f, a3 = 0.f;
    int i = beg;
    for (; i + 4 <= end; i += 4) {
        int s[4];
        float w[4];
        uint2 hv[4];
#pragma unroll
        for (int u = 0; u < 4; u++) {
            s[u] = __builtin_nontemporal_load(csr + i + u);
            w[u] = __builtin_nontemporal_load(csr_w + i + u);
        }
#pragma unroll
        for (int u = 0; u < 4; u++) hv[u] = *(const uint2*)(xh + (size_t)s[u] * 256 + c0);
#pragma unroll
        for (int u = 0; u < 4; u++) {
            a0 = fmaf(h2f_lo(hv[u].x), w[u], a0);
            a1 = fmaf(h2f_hi(hv[u].x), w[u], a1);
            a2 = fmaf(h2f_lo(hv[u].y), w[u], a2);
            a3 = fmaf(h2f_hi(hv[u].y), w[u], a3);
        }
    }
    for (; i < end; i++) {
        const int sv = csr[i];
        const float w = csr_w[i];
        uint2 hv = *(const uint2*)(xh + (size_t)sv * 256 + c0);
        a0 = fmaf(h2f_lo(hv.x), w, a0);
        a1 = fmaf(h2f_hi(hv.x), w, a1);
        a2 = fmaf(h2f_lo(hv.y), w, a2);
        a3 = fmaf(h2f_hi(hv.y), w, a3);
    }
    {
        const float dn = dinv[node];
        const float ws = dn * dn;
        const float4 xv = *(const float4*)(x + (size_t)node * 256 + c0);
        a0 = fmaf(xv.x, ws, a0);
        a1 = fmaf(xv.y, ws, a1);
        a2 = fmaf(xv.z, ws, a2);
        a3 = fmaf(xv.w, ws, a3);
    }
    u32x2 ho;
    ho.x = (unsigned)f2h(a0) | ((unsigned)f2h(a1) << 16);
    ho.y = (unsigned)f2h(a2) | ((unsigned)f2h(a3) << 16);
    __builtin_nontemporal_store(ho, (u32x2*)(oh + (size_t)node * 256 + c0));
}

// ---------------- layer-2 aggregation (h1 fp16 gather, F=512) --------------
__global__ __launch_bounds__(256)
void agg_h_kernel(const u16* __restrict__ hin, u16* __restrict__ oh,
                  const int* __restrict__ csr, const float* __restrict__ csr_w,
                  const int* __restrict__ rs, const float* __restrict__ dinv, int n) {
    const int node = blockIdx.x * 4 + (threadIdx.x >> 6);
    if (node >= n) return;
    const int lane = threadIdx.x & 63;
    const int c0 = lane * 8;
    const int beg = rs[node], end = rs[node + 1];
    float a[8];
#pragma unroll
    for (int j = 0; j < 8; j++) a[j] = 0.f;
    int i = beg;
    for (; i + 4 <= end; i += 4) {
        int s[4];
        float w[4];
        uint4 hv[4];
#pragma unroll
        for (int u = 0; u < 4; u++) {
            s[u] = __builtin_nontemporal_load(csr + i + u);
            w[u] = __builtin_nontemporal_load(csr_w + i + u);
        }
#pragma unroll
        for (int u = 0; u < 4; u++) hv[u] = *(const uint4*)(hin + (size_t)s[u] * 512 + c0);
#pragma unroll
        for (int u = 0; u < 4; u++) {
            a[0] = fmaf(h2f_lo(hv[u].x), w[u], a[0]);
            a[1] = fmaf(h2f_hi(hv[u].x), w[u], a[1]);
            a[2] = fmaf(h2f_lo(hv[u].y), w[u], a[2]);
            a[3] = fmaf(h2f_hi(hv[u].y), w[u], a[3]);
            a[4] = fmaf(h2f_lo(hv[u].z), w[u], a[4]);
            a[5] = fmaf(h2f_hi(hv[u].z), w[u], a[5]);
            a[6] = fmaf(h2f_lo(hv[u].w), w[u], a[6]);
            a[7] = fmaf(h2f_hi(hv[u].w), w[u], a[7]);
        }
    }
    for (; i < end; i++) {
        const int sv = csr[i];
        const float w = csr_w[i];
        uint4 hv = *(const uint4*)(hin + (size_t)sv * 512 + c0);
        a[0] = fmaf(h2f_lo(hv.x), w, a[0]);
        a[1] = fmaf(h2f_hi(hv.x), w, a[1]);
        a[2] = fmaf(h2f_lo(hv.y), w, a[2]);
        a[3] = fmaf(h2f_hi(hv.y), w, a[3]);
        a[4] = fmaf(h2f_lo(hv.z), w, a[4]);
        a[5] = fmaf(h2f_hi(hv.z), w, a[5]);
        a[6] = fmaf(h2f_lo(hv.w), w, a[6]);
        a[7] = fmaf(h2f_hi(hv.w), w, a[7]);
    }
    {
        const float dn = dinv[node];
        const float ws = dn * dn;
        uint4 hv = *(const uint4*)(hin + (size_t)node * 512 + c0);
        a[0] = fmaf(h2f_lo(hv.x), ws, a[0]);
        a[1] = fmaf(h2f_hi(hv.x), ws, a[1]);
        a[2] = fmaf(h2f_lo(hv.y), ws, a[2]);
        a[3] = fmaf(h2f_hi(hv.y), ws, a[3]);
        a[4] = fmaf(h2f_lo(hv.z), ws, a[4]);
        a[5] = fmaf(h2f_hi(hv.z), ws, a[5]);
        a[6] = fmaf(h2f_lo(hv.w), ws, a[6]);
        a[7] = fmaf(h2f_hi(hv.w), ws, a[7]);
    }
    u32x4 ho;
#pragma unroll
    for (int j = 0; j < 4; j++)
        ho[j] = (unsigned)f2h(a[2 * j]) | ((unsigned)f2h(a[2 * j + 1]) << 16);
    __builtin_nontemporal_store(ho, (u32x4*)(oh + (size_t)node * 512 + c0));
}

// ---------------- fp16 MFMA GEMM, BM=128 BN=256, 8 waves (2x4) -------------
// C[M,Nn] = A[M,K] @ Bt[Nn,K]^T, fp16 in, fp32 accum.
// global_load_lds staging, pre-swizzled global source, linear LDS.
// OUTMODE: 0 = fp32 Cf, 2 = fp16 Ch.
template <bool RELU, int OUTMODE>
__global__ __launch_bounds__(512)
void gemm256_kernel(const u16* __restrict__ A, const u16* __restrict__ Bt,
                    const float* __restrict__ bias,
                    float* __restrict__ Cf, u16* __restrict__ Ch,
                    int M, int K, int Nn) {
    __shared__ u16 sA[128 * 32], sB[256 * 32];

    const int gx = gridDim.x;
    const int nwg = gx * gridDim.y;
    const int orig = blockIdx.y * gx + blockIdx.x;
    const int q8 = nwg >> 3, r8 = nwg & 7;
    const int xcd = orig & 7, lin = orig >> 3;
    const int wg = (xcd < r8 ? xcd * (q8 + 1) : r8 * (q8 + 1) + (xcd - r8) * q8) + lin;
    const int mt = wg / gx;
    const int nt = wg - mt * gx;
    const int m0 = mt * 128, n0 = nt * 256;

    const int tid = threadIdx.x;
    const int lane = tid & 63;
    const int wid = tid >> 6;
    const int wm = (wid >> 2) * 64;
    const int wn = (wid & 3) * 64;

    // staging: round = 128 rows x 32 cols; 512 thr x 16B
    const int srow = tid >> 2;
    const int gslot = (tid & 3) ^ ((tid >> 3) & 3);
    const int lbase = wid * 16 * 32;  // u16 units

    const u16* gA  = A  + (size_t)(m0 + srow) * K + gslot * 8;
    const u16* gB0 = Bt + (size_t)(n0 + srow) * K + gslot * 8;
    const u16* gB1 = Bt + (size_t)(n0 + 128 + srow) * K + gslot * 8;

    int offA[4], offB[4];
    const int q = lane >> 4;
#pragma unroll
    for (int i = 0; i < 4; i++) {
        int r = wm + i * 16 + (lane & 15);
        offA[i] = r * 32 + ((q ^ ((r >> 1) & 3)) * 8);
    }
#pragma unroll
    for (int j = 0; j < 4; j++) {
        int r = wn + j * 16 + (lane & 15);
        offB[j] = r * 32 + ((q ^ ((r >> 1) & 3)) * 8);
    }

    f32x4 acc[4][4];
#pragma unroll
    for (int i = 0; i < 4; i++)
#pragma unroll
        for (int j = 0; j < 4; j++) acc[i][j] = (f32x4){0.f, 0.f, 0.f, 0.f};

    auto stage = [&](int k0) {
        gload16(gA + k0, sA + lbase);
        gload16(gB0 + k0, sB + lbase);
        gload16(gB1 + k0, sB + 128 * 32 + lbase);
    };

    stage(0);
    for (int k0 = 0; k0 < K; k0 += 32) {
        __syncthreads();  // drain vmcnt: staged tile visible
        f16x8 af[4], bf[4];
#pragma unroll
        for (int i = 0; i < 4; i++) af[i] = *(const f16x8*)(sA + offA[i]);
#pragma unroll
        for (int j = 0; j < 4; j++) bf[j] = *(const f16x8*)(sB + offB[j]);
#pragma unroll
        for (int i = 0; i < 4; i++)
#pragma unroll
            for (int j = 0; j < 4; j++)
                acc[i][j] = __builtin_amdgcn_mfma_f32_16x16x32_f16(af[i], bf[j], acc[i][j], 0, 0, 0);
        __syncthreads();  // LDS reads done
        if (k0 + 32 < K) stage(k0 + 32);
    }

    const int cn = lane & 15;
    const int cm = (lane >> 4) * 4;
#pragma unroll
    for (int i = 0; i < 4; i++) {
#pragma unroll
        for (int j = 0; j < 4; j++) {
            const int col = n0 + wn + j * 16 + cn;
            const float bv = bias[col];
#pragma unroll
            for (int r = 0; r < 4; r++) {
                const int row = m0 + wm + i * 16 + cm + r;
                if (row < M) {
                    float v = acc[i][j][r] + bv;
                    if (RELU) v = fmaxf(v, 0.f);
                    if constexpr (OUTMODE == 2) {
                        Ch[(size_t)row * Nn + col] = f2h(v);
                    } else {
                        Cf[(size_t)row * Nn + col] = v;
                    }
                }
            }
        }
    }
}

// ---------------- fp16 MFMA GEMM, BM=128 BN=64, 4 waves (2x2) --------------
template <bool RELU>
__global__ __launch_bounds__(256)
void gemm64_kernel(const u16* __restrict__ A, const u16* __restrict__ Bt,
                   const float* __restrict__ bias, float* __restrict__ Cf,
                   int M, int K, int Nn) {
    __shared__ u16 sA[128 * 32], sB[64 * 32];

    const int nwg = gridDim.y;
    const int orig = blockIdx.y;
    const int q8 = nwg >> 3, r8 = nwg & 7;
    const int xcd = orig & 7, lin = orig >> 3;
    const int wg = (xcd < r8 ? xcd * (q8 + 1) : r8 * (q8 + 1) + (xcd - r8) * q8) + lin;
    const int m0 = wg * 128, n0 = 0;

    const int tid = threadIdx.x;
    const int lane = tid & 63;
    const int wid = tid >> 6;
    const int wm = (wid >> 1) * 64;
    const int wn = (wid & 1) * 32;

    const int srow = tid >> 2;  // 0..63
    const int gslot = (tid & 3) ^ ((tid >> 3) & 3);
    const int lbase = wid * 16 * 32;

    const u16* gA0 = A + (size_t)(m0 + srow) * K + gslot * 8;
    const u16* gA1 = A + (size_t)(m0 + 64 + srow) * K + gslot * 8;
    const u16* gB0 = Bt + (size_t)(n0 + srow) * K + gslot * 8;

    int offA[4], offB[2];
    const int q = lane >> 4;
#pragma unroll
    for (int i = 0; i < 4; i++) {
        int r = wm + i * 16 + (lane & 15);
        offA[i] = r * 32 + ((q ^ ((r >> 1) & 3)) * 8);
    }
#pragma unroll
    for (int j = 0; j < 2; j++) {
        int r = wn + j * 16 + (lane & 15);
        offB[j] = r * 32 + ((q ^ ((r >> 1) & 3)) * 8);
    }

    f32x4 acc[4][2];
#pragma unroll
    for (int i = 0; i < 4; i++)
#pragma unroll
        for (int j = 0; j < 2; j++) acc[i][j] = (f32x4){0.f, 0.f, 0.f, 0.f};

    auto stage = [&](int k0) {
        gload16(gA0 + k0, sA + lbase);
        gload16(gA1 + k0, sA + 64 * 32 + lbase);
        gload16(gB0 + k0, sB + lbase);
    };

    stage(0);
    for (int k0 = 0; k0 < K; k0 += 32) {
        __syncthreads();
        f16x8 af[4], bf[2];
#pragma unroll
        for (int i = 0; i < 4; i++) af[i] = *(const f16x8*)(sA + offA[i]);
#pragma unroll
        for (int j = 0; j < 2; j++) bf[j] = *(const f16x8*)(sB + offB[j]);
#pragma unroll
        for (int i = 0; i < 4; i++)
#pragma unroll
            for (int j = 0; j < 2; j++)
                acc[i][j] = __builtin_amdgcn_mfma_f32_16x16x32_f16(af[i], bf[j], acc[i][j], 0, 0, 0);
        __syncthreads();
        if (k0 + 32 < K) stage(k0 + 32);
    }

    const int cn = lane & 15;
    const int cm = (lane >> 4) * 4;
#pragma unroll
    for (int i = 0; i < 4; i++) {
#pragma unroll
        for (int j = 0; j < 2; j++) {
            const int col = wn + j * 16 + cn;
            const float bv = bias[col];
#pragma unroll
            for (int r = 0; r < 4; r++) {
                const int row = m0 + wm + i * 16 + cm + r;
                if (row < M) {
                    float v = acc[i][j][r] + bv;
                    if (RELU) v = fmaxf(v, 0.f);
                    Cf[(size_t)row * Nn + col] = v;
                }
            }
        }
    }
}

// ---------------------------------------------------------------------------
extern "C" void kernel_launch(void* const* d_in, const int* in_sizes, int n_in,
                              void* d_out, int out_size, void* d_ws, size_t ws_size,
                              hipStream_t stream) {
    const float* x  = (const float*)d_in[0];
    const int*   ei = (const int*)d_in[1];
    const float* W1 = (const float*)d_in[2];
    const float* b1 = (const float*)d_in[3];
    const float* W2 = (const float*)d_in[4];
    const float* b2 = (const float*)d_in[5];
    const float* Wl = (const float*)d_in[6];
    const float* bl = (const float*)d_in[7];
    float* out = (float*)d_out;

    const int N = in_sizes[0] / 256;  // 50000
    const int E = in_sizes[1] / 2;    // 800000
    const int Mpad = ((N + 127) / 128) * 128;  // 50048
    const int nb = (N + 1023) / 1024;          // scan blocks
    const int* src = ei;
    const int* dst = ei + E;

    size_t off = 0;
    auto alloc = [&](size_t bytes) -> void* {
        void* p = (char*)d_ws + off;
        off += (bytes + 255) & ~(size_t)255;
        return p;
    };
    float* deg       = (float*)alloc((size_t)N * 4);
    float* dinv      = (float*)alloc((size_t)N * 4);
    int*   part      = (int*)alloc((size_t)1024 * 4);
    int*   row_start = (int*)alloc((size_t)(N + 1) * 4);
    int*   cursor    = (int*)alloc((size_t)N * 4);
    int*   csr       = (int*)alloc((size_t)E * 4);
    float* csr_w     = (float*)alloc((size_t)E * 4);
    u16*   xh        = (u16*)alloc((size_t)N * 256 * 2);
    u16*   bt1 = (u16*)alloc((size_t)512 * 256 * 2);
    u16*   bt2 = (u16*)alloc((size_t)512 * 512 * 2);
    u16*   bt3 = (u16*)alloc((size_t)64 * 512 * 2);
    u16*   slabA = (u16*)alloc((size_t)Mpad * 512 * 2);  // a1h then a2h
    u16*   slabH = (u16*)alloc((size_t)Mpad * 512 * 2);  // h1h then h2h
    (void)ws_size;

    u16* a1h = slabA;   // [Mpad,256] agg1->gemm1
    u16* a2h = slabA;   // [Mpad,512] agg2->gemm2 (a1h dead)
    u16* h1h = slabH;   // [Mpad,512] gemm1->agg2
    u16* h2h = slabH;   // [Mpad,512] gemm2->gemm3 (h1h dead)

    init_deg_kernel<<<(N + 255) / 256, 256, 0, stream>>>(deg, N);
    count_deg_kernel<<<(E + 255) / 256, 256, 0, stream>>>(dst, deg, E);
    scan1_kernel<<<nb, 1024, 0, stream>>>(deg, part, N);
    scan2_kernel<<<1, 1024, 0, stream>>>(part, nb);
    scan3_kernel<<<nb, 1024, 0, stream>>>(deg, part, dinv, row_start, cursor, N);
    bucket_kernel<<<(E + 255) / 256, 256, 0, stream>>>(src, dst, row_start, cursor, csr, csr_w, dinv, E);

    wtrans_kernel<<<(512 * 32 + 255) / 256, 256, 0, stream>>>(W1, bt1, 256, 512);
    wtrans_kernel<<<(512 * 64 + 255) / 256, 256, 0, stream>>>(W2, bt2, 512, 512);
    wtrans_kernel<<<(64 * 64 + 255) / 256, 256, 0, stream>>>(Wl, bt3, 512, 64);
    xsplit_kernel<<<((N * 32) + 255) / 256, 256, 0, stream>>>(x, xh, (size_t)N * 32);

    // layer 1
    agg_x_kernel<<<(N + 3) / 4, 256, 0, stream>>>(x, xh, a1h, csr, csr_w, row_start, dinv, N);
    gemm256_kernel<true, 2><<<dim3(2, Mpad / 128), 512, 0, stream>>>(
        a1h, bt1, b1, nullptr, h1h, N, 256, 512);

    // layer 2
    agg_h_kernel<<<(N + 3) / 4, 256, 0, stream>>>(h1h, a2h, csr, csr_w, row_start, dinv, N);
    gemm256_kernel<true, 2><<<dim3(2, Mpad / 128), 512, 0, stream>>>(
        a2h, bt2, b2, nullptr, h2h, N, 512, 512);

    // output projection
    gemm64_kernel<false><<<dim3(1, Mpad / 128), 256, 0, stream>>>(
        h2h, bt3, bl, out, N, 512, 64);
}